// Round 4
// baseline (487.869 us; speedup 1.0000x reference)
//
#include <hip/hip_runtime.h>
#include <hip/hip_bf16.h>

typedef float f32x4 __attribute__((ext_vector_type(4)));
typedef __bf16 bf16x8 __attribute__((ext_vector_type(8)));
typedef unsigned short u16x8 __attribute__((ext_vector_type(8)));
typedef unsigned short u16x4 __attribute__((ext_vector_type(4)));

#define QSCALE 0.180336881f  /* 0.125 * log2(e): folds attn scale + exp2 domain into Q */

__device__ __forceinline__ unsigned short f2bf(float f) {
  union { float f; unsigned int u; } v; v.f = f;
  return (unsigned short)((v.u + 0x7FFFu + ((v.u >> 16) & 1u)) >> 16);
}

__device__ __forceinline__ f32x4 mfma16(bf16x8 a, bf16x8 b, f32x4 c) {
  return __builtin_amdgcn_mfma_f32_16x16x32_bf16(a, b, c, 0, 0, 0);
}

__device__ __forceinline__ void gload16(const unsigned short* g, unsigned short* l) {
  __builtin_amdgcn_global_load_lds(
      (const __attribute__((address_space(1))) void*)g,
      (__attribute__((address_space(3))) void*)l, 16, 0, 0);
}

// ---------------- small utility kernels ----------------

__global__ void concat_bias_k(const float* __restrict__ qb, const float* __restrict__ kb,
                              const float* __restrict__ vb, float* __restrict__ out) {
  const int i = blockIdx.x * 256 + threadIdx.x;
  if (i >= 3072) return;
  const float* s = (i < 1024) ? qb : (i < 2048 ? kb : vb);
  out[i] = s[i & 1023] * (i < 1024 ? QSCALE : 1.0f);
}

// fp32 [R,C] -> bf16 [C,R]
__global__ void tcvt_k(const float* __restrict__ in, unsigned short* __restrict__ out,
                       int R, int C) {
  __shared__ float tile[32][33];
  const int x = blockIdx.x * 32 + threadIdx.x;
  const int y0 = blockIdx.y * 32;
#pragma unroll
  for (int i = 0; i < 32; i += 8)
    tile[threadIdx.y + i][threadIdx.x] = in[(size_t)(y0 + threadIdx.y + i) * C + x];
  __syncthreads();
  const int ox = y0 + threadIdx.x;
  const int oy0 = blockIdx.x * 32;
#pragma unroll
  for (int i = 0; i < 32; i += 8)
    out[(size_t)(oy0 + threadIdx.y + i) * R + ox] = f2bf(tile[threadIdx.x][threadIdx.y + i]);
}

__global__ void cvt_k(const float* __restrict__ in, unsigned short* __restrict__ out, int n) {
  const int i = (blockIdx.x * 256 + threadIdx.x) * 4;
  if (i >= n) return;
  const f32x4 v = *(const f32x4*)(in + i);
  u16x4 o;
#pragma unroll
  for (int k = 0; k < 4; ++k) o[k] = f2bf(v[k]);
  *(u16x4*)(out + i) = o;
}

// V-transpose: QKV[b][s][2048 + h*64 + d] -> VT[(b*16+h)][d][s]  (bf16)
__global__ void vtr_k(const unsigned short* __restrict__ QKV, unsigned short* __restrict__ VT) {
  __shared__ unsigned short tile[32][33];
  const int bh = blockIdx.z, b = bh >> 4, h = bh & 15;
  const int s0 = blockIdx.x * 32, d0 = blockIdx.y * 32;
  const unsigned short* src = QKV + (size_t)b * 2048 * 3072 + 2048 + h * 64;
#pragma unroll
  for (int i = 0; i < 32; i += 8)
    tile[threadIdx.y + i][threadIdx.x] = src[(size_t)(s0 + threadIdx.y + i) * 3072 + d0 + threadIdx.x];
  __syncthreads();
  unsigned short* dst = VT + (size_t)bh * 64 * 2048;
#pragma unroll
  for (int i = 0; i < 32; i += 8)
    dst[(size_t)(d0 + threadIdx.y + i) * 2048 + s0 + threadIdx.x] = tile[threadIdx.x][threadIdx.y + i];
}

// Wqkv^T[(m*1024 + h*64 + e)*1024 + d] = sum_r U_m[d,h,r] * V_m[h,r,e]  (Q part scaled)
__global__ __launch_bounds__(256) void wqkv_pre_k(
    const float* __restrict__ qU, const float* __restrict__ qV,
    const float* __restrict__ kU, const float* __restrict__ kV,
    const float* __restrict__ vU, const float* __restrict__ vV,
    unsigned short* __restrict__ WT) {
  __shared__ float Us[64][48];
  __shared__ float Vs[48][64];
  const int m = blockIdx.y >> 4, h = blockIdx.y & 15;
  const int d0 = blockIdx.x * 64;
  const float* U = (m == 0) ? qU : (m == 1 ? kU : vU);
  const float* V = (m == 0) ? qV : (m == 1 ? kV : vV);
  const float qs = (m == 0) ? QSCALE : 1.0f;
  const int t = threadIdx.x;
  for (int idx = t; idx < 64 * 48; idx += 256) {
    const int d = idx / 48, r = idx - d * 48;
    Us[d][r] = U[(size_t)(d0 + d) * 768 + h * 48 + r];
  }
  for (int idx = t; idx < 48 * 64; idx += 256) {
    const int r = idx >> 6, e = idx & 63;
    Vs[r][e] = V[(h * 48 + r) * 64 + e];
  }
  __syncthreads();
  const int e = t & 63, dg = t >> 6;
  for (int j = 0; j < 16; ++j) {
    const int d = dg * 16 + j;
    float s = 0.f;
#pragma unroll
    for (int r = 0; r < 48; ++r) s = fmaf(Us[d][r], Vs[r][e], s);
    WT[(size_t)(m * 1024 + h * 64 + e) * 1024 + d0 + d] = f2bf(s * qs);
  }
}

// LayerNorm over D=1024, fp32 in, bf16 out. One block per row.
__global__ __launch_bounds__(256) void ln_k(
    const float* __restrict__ in, const float* __restrict__ gw,
    const float* __restrict__ bw, unsigned short* __restrict__ out) {
  const int row = blockIdx.x, t = threadIdx.x;
  const f32x4 v = *(const f32x4*)(in + (size_t)row * 1024 + t * 4);
  float s = v[0] + v[1] + v[2] + v[3];
  float ss = v[0] * v[0] + v[1] * v[1] + v[2] * v[2] + v[3] * v[3];
#pragma unroll
  for (int off = 1; off < 64; off <<= 1) {
    s += __shfl_xor(s, off);
    ss += __shfl_xor(ss, off);
  }
  __shared__ float red[8];
  if ((t & 63) == 0) { red[(t >> 6) * 2] = s; red[(t >> 6) * 2 + 1] = ss; }
  __syncthreads();
  s = red[0] + red[2] + red[4] + red[6];
  ss = red[1] + red[3] + red[5] + red[7];
  const float mean = s * (1.0f / 1024.0f);
  const float rstd = rsqrtf(ss * (1.0f / 1024.0f) - mean * mean + 1e-5f);
  const f32x4 g4 = *(const f32x4*)(gw + t * 4);
  const f32x4 b4 = *(const f32x4*)(bw + t * 4);
  u16x4 o;
#pragma unroll
  for (int i = 0; i < 4; ++i) o[i] = f2bf((v[i] - mean) * rstd * g4[i] + b4[i]);
  *(u16x4*)(out + (size_t)row * 1024 + t * 4) = o;
}

// ---------------- generic bf16 MFMA GEMM (double-buffered global_load_lds) ----------------
// C[M,N] = A[M,K] @ Bt[N,K]^T. BM=128, BN in {64,128}, 256 threads = 4 waves (2x2).
// 2-phase pipeline: one barrier per K-step; next tile's async loads issued before
// the current tile's ds_read+MFMA so HBM/L2 latency hides under compute.
template <int BN, int EPI, int OUTBF>
__global__ __launch_bounds__(256) void gemm_k(
    const unsigned short* __restrict__ A, const unsigned short* __restrict__ Bt,
    const float* __restrict__ bias, const float* __restrict__ resid,
    void* __restrict__ Cout, int M, int N, int K) {
  constexpr int FN = BN / 32;
  __shared__ unsigned short As[2][128 * 32];
  __shared__ unsigned short Bs[2][BN * 32];
  const int t = threadIdx.x;
  const int lane = t & 63, wid = t >> 6;
  const int m0 = blockIdx.y * 128, n0 = blockIdx.x * BN;
  const int wm = (wid >> 1) * 64, wn = (wid & 1) * (BN / 2);
  const int fr = lane & 15, fg = (lane >> 4) * 8;

  f32x4 acc[4][FN];
#pragma unroll
  for (int i = 0; i < 4; ++i)
#pragma unroll
    for (int j = 0; j < FN; ++j) acc[i][j] = (f32x4){0.f, 0.f, 0.f, 0.f};

  // staging: 1KiB chunk = 16 rows x 32 cols; lane l -> byte offset 16*l (linear, HW-compatible)
  const int sub = lane >> 2, c8 = (lane & 3) * 8;
  const int loff = wid * 512 + sub * 32 + c8;
  const unsigned short* Ag0 = A + (size_t)(m0 + wid * 16 + sub) * K + c8;
  const unsigned short* Ag1 = A + (size_t)(m0 + (wid + 4) * 16 + sub) * K + c8;
  const unsigned short* Bg0 = Bt + (size_t)(n0 + wid * 16 + sub) * K + c8;
  const unsigned short* Bg1 = Bt + (size_t)(n0 + ((wid + 4) & (BN / 16 - 1)) * 16 + sub) * K + c8;

  const int nk = K >> 5;
  // prologue: stage tile 0 into buf 0
  gload16(Ag0, &As[0][loff]);
  gload16(Ag1, &As[0][loff + 2048]);
  gload16(Bg0, &Bs[0][loff]);
  if (BN == 128) gload16(Bg1, &Bs[0][loff + 2048]);

  for (int kt = 0; kt < nk; ++kt) {
    const int cur = kt & 1;
    __syncthreads();  // drains vmcnt: buf[cur] staged; prev iter's reads of buf[cur^1] done
    if (kt + 1 < nk) {
      const int ke = (kt + 1) * 32;
      gload16(Ag0 + ke, &As[cur ^ 1][loff]);
      gload16(Ag1 + ke, &As[cur ^ 1][loff + 2048]);
      gload16(Bg0 + ke, &Bs[cur ^ 1][loff]);
      if (BN == 128) gload16(Bg1 + ke, &Bs[cur ^ 1][loff + 2048]);
    }
    bf16x8 af[4], bfr[FN];
#pragma unroll
    for (int i = 0; i < 4; ++i) af[i] = *(const bf16x8*)&As[cur][(wm + i * 16 + fr) * 32 + fg];
#pragma unroll
    for (int j = 0; j < FN; ++j) bfr[j] = *(const bf16x8*)&Bs[cur][(wn + j * 16 + fr) * 32 + fg];
#pragma unroll
    for (int i = 0; i < 4; ++i)
#pragma unroll
      for (int j = 0; j < FN; ++j) acc[i][j] = mfma16(af[i], bfr[j], acc[i][j]);
  }

#pragma unroll
  for (int j = 0; j < FN; ++j) {
    const int col = n0 + wn + j * 16 + fr;
    const float bval = (EPI >= 1) ? bias[col] : 0.0f;
#pragma unroll
    for (int i = 0; i < 4; ++i) {
#pragma unroll
      for (int r = 0; r < 4; ++r) {
        const int row = m0 + wm + i * 16 + ((lane >> 4) << 2) + r;
        float v = acc[i][j][r] + bval;
        if (EPI == 2) {  // gelu tanh-approx: v * sigmoid(2z)
          const float z = 0.7978845608028654f * (v + 0.044715f * v * v * v);
          v = v - v / (__expf(2.0f * z) + 1.0f);
        }
        if (EPI == 3) v += resid[(size_t)row * N + col];
        if (OUTBF)
          ((unsigned short*)Cout)[(size_t)row * N + col] = f2bf(v);
        else
          ((float*)Cout)[(size_t)row * N + col] = v;
      }
    }
  }
}

// ---------------- causal flash attention (barrier-free, L2-direct K/V) ----------------
// Q pre-scaled by 0.125*log2e (exp2 domain). K frags from QKV, V frags from VT[bh][dh][S].
// grid (32, 32): qt = 31 - bx (big blocks first), bh = by. 4 independent waves,
// wave w owns q rows qt*64+16w..+15. Row-sum via ones-fragment MFMA (5th accumulator).
__global__ __launch_bounds__(256) void attn_k(
    const unsigned short* __restrict__ QKV, const unsigned short* __restrict__ VT,
    unsigned short* __restrict__ ctx) {
  __shared__ __bf16 Ps[4][16][72];  // per-wave P [qrow][key]
  const int qt = 31 - blockIdx.x, bh = blockIdx.y;
  const int b = bh >> 4, h = bh & 15;
  const int t = threadIdx.x, lane = t & 63, w = t >> 6;
  const int g = lane >> 4, c = lane & 15;
  const int q0 = qt * 64;
  const size_t base = (size_t)b * 2048 * 3072;

  const unsigned short* qp = QKV + base + (size_t)(q0 + w * 16 + c) * 3072 + h * 64 + g * 8;
  const bf16x8 qf0 = *(const bf16x8*)qp;
  const bf16x8 qf1 = *(const bf16x8*)(qp + 32);

  bf16x8 onef;
#pragma unroll
  for (int i = 0; i < 8; ++i) onef[i] = (__bf16)1.0f;

  // K frag base: row (kt*64 + t16*16 + c), col g*8 (+32)
  const unsigned short* Kb = QKV + base + 1024 + h * 64 + (size_t)c * 3072 + g * 8;
  // V frag base: row (d*16 + c), key (kt*64 + ks*32 + g*8)
  const unsigned short* Vb = VT + (size_t)bh * 64 * 2048 + g * 8;

  f32x4 o[4];
#pragma unroll
  for (int d = 0; d < 4; ++d) o[d] = (f32x4){0.f, 0.f, 0.f, 0.f};
  f32x4 ol = (f32x4){0.f, 0.f, 0.f, 0.f};
  float mrow[4];
#pragma unroll
  for (int r = 0; r < 4; ++r) mrow[r] = -1e30f;

  for (int kt = 0; kt <= qt; ++kt) {
    const unsigned short* Kt = Kb + (size_t)kt * 64 * 3072;
    bf16x8 kf[4][2];
#pragma unroll
    for (int t16 = 0; t16 < 4; ++t16) {
      kf[t16][0] = *(const bf16x8*)(Kt + (size_t)t16 * 16 * 3072);
      kf[t16][1] = *(const bf16x8*)(Kt + (size_t)t16 * 16 * 3072 + 32);
    }
    const unsigned short* Vt_ = Vb + kt * 64;
    bf16x8 vf[2][4];
#pragma unroll
    for (int ks = 0; ks < 2; ++ks)
#pragma unroll
      for (int d = 0; d < 4; ++d)
        vf[ks][d] = *(const bf16x8*)(Vt_ + (size_t)(d * 16 + c) * 2048 + ks * 32);

    // S = Q K^T (already in exp2 domain). C layout: col=key=c, row=q=4g+r
    f32x4 s4[4];
    __builtin_amdgcn_s_setprio(1);
#pragma unroll
    for (int t16 = 0; t16 < 4; ++t16) {
      f32x4 a = (f32x4){0.f, 0.f, 0.f, 0.f};
      a = mfma16(qf0, kf[t16][0], a);
      a = mfma16(qf1, kf[t16][1], a);
      s4[t16] = a;
    }
    __builtin_amdgcn_s_setprio(0);
    if (kt == qt) {  // diagonal tile: causal mask
      const int qbase = q0 + w * 16 + g * 4;
      const int kbase = kt * 64 + c;
#pragma unroll
      for (int t16 = 0; t16 < 4; ++t16)
#pragma unroll
        for (int r = 0; r < 4; ++r)
          if (kbase + t16 * 16 > qbase + r) s4[t16][r] = -1e30f;
    }
    // online softmax: max over 16 key-lanes (per 16-lane group)
    float mx[4];
#pragma unroll
    for (int r = 0; r < 4; ++r)
      mx[r] = fmaxf(fmaxf(s4[0][r], s4[1][r]), fmaxf(s4[2][r], s4[3][r]));
#pragma unroll
    for (int off = 1; off < 16; off <<= 1)
#pragma unroll
      for (int r = 0; r < 4; ++r) mx[r] = fmaxf(mx[r], __shfl_xor(mx[r], off));
    float fac[4];
#pragma unroll
    for (int r = 0; r < 4; ++r) {
      const float mn = fmaxf(mrow[r], mx[r]);
      fac[r] = exp2f(mrow[r] - mn);
      mrow[r] = mn;
    }
#pragma unroll
    for (int t16 = 0; t16 < 4; ++t16)
#pragma unroll
      for (int r = 0; r < 4; ++r)
        Ps[w][g * 4 + r][t16 * 16 + c] = (__bf16)exp2f(s4[t16][r] - mrow[r]);
#pragma unroll
    for (int d = 0; d < 4; ++d)
#pragma unroll
      for (int r = 0; r < 4; ++r) o[d][r] *= fac[r];
#pragma unroll
    for (int r = 0; r < 4; ++r) ol[r] *= fac[r];
    // O += P V ; row-sum l += P @ ones  (same rescale path)
    __builtin_amdgcn_s_setprio(1);
#pragma unroll
    for (int ks = 0; ks < 2; ++ks) {
      const bf16x8 pf = *(const bf16x8*)&Ps[w][c][ks * 32 + g * 8];
#pragma unroll
      for (int d = 0; d < 4; ++d) o[d] = mfma16(pf, vf[ks][d], o[d]);
      ol = mfma16(pf, onef, ol);
    }
    __builtin_amdgcn_s_setprio(0);
  }
#pragma unroll
  for (int d = 0; d < 4; ++d)
#pragma unroll
    for (int r = 0; r < 4; ++r) {
      const float v = o[d][r] / ol[r];
      ctx[(size_t)(b * 2048 + q0 + w * 16 + g * 4 + r) * 1024 + h * 64 + d * 16 + c] = f2bf(v);
    }
}

// ---------------- launch ----------------

extern "C" void kernel_launch(void* const* d_in, const int* in_sizes, int n_in,
                              void* d_out, int out_size, void* d_ws, size_t ws_size,
                              hipStream_t stream) {
  const float* hidden = (const float*)d_in[0];
  const float* ln1g = (const float*)d_in[1];
  const float* ln1b = (const float*)d_in[2];
  const float* ln2g = (const float*)d_in[3];
  const float* ln2b = (const float*)d_in[4];
  const float* qU = (const float*)d_in[5];
  const float* qV = (const float*)d_in[6];
  const float* qb = (const float*)d_in[7];
  const float* kU = (const float*)d_in[8];
  const float* kV = (const float*)d_in[9];
  const float* kb = (const float*)d_in[10];
  const float* vU = (const float*)d_in[11];
  const float* vV = (const float*)d_in[12];
  const float* vb = (const float*)d_in[13];
  const float* outU = (const float*)d_in[14];
  const float* outV = (const float*)d_in[15];
  const float* outb = (const float*)d_in[16];
  const float* fc1U = (const float*)d_in[17];
  const float* fc1V = (const float*)d_in[18];
  const float* fc1b = (const float*)d_in[19];
  const float* fc2U = (const float*)d_in[20];
  const float* fc2V = (const float*)d_in[21];
  const float* fc2b = (const float*)d_in[22];
  float* out = (float*)d_out;

  // workspace carve, lifetime-based aliasing
  char* p = (char*)d_ws;
  unsigned short* x1x2 = (unsigned short*)p; p += (size_t)4096 * 1024 * 2;   // x1 (LN1), later x2 (LN2)
  unsigned short* WqT_t1 = (unsigned short*)p; p += (size_t)3072 * 1024 * 2; // Wqkv^T, later t1
  float* bqkv = (float*)p; p += 3072 * 4;
  char* bigA = p; p += (size_t)4096 * 3072 * 2 + (size_t)4096 * 1024 * 2;    // QKV + ctx, later hmid
  unsigned short* QKV = (unsigned short*)bigA;
  unsigned short* ctxb = (unsigned short*)(bigA + (size_t)4096 * 3072 * 2);
  unsigned short* hmid = (unsigned short*)bigA;
  char* wo = p; p += (size_t)1024 * 768 * 2 * 2 + (size_t)1024 * 1024 * 2;   // outU,outV^T,Wout^T, later t2
  unsigned short* outUb = (unsigned short*)wo;
  unsigned short* outVT = (unsigned short*)(wo + (size_t)1024 * 768 * 2);
  unsigned short* WoutT = (unsigned short*)(wo + (size_t)1024 * 768 * 2 * 2);
  unsigned short* t2 = (unsigned short*)wo;
  float* hbuf = (float*)p; p += (size_t)4096 * 1024 * 4;                     // h (fp32 residual); VT aliases pre-attn
  unsigned short* VT = (unsigned short*)hbuf;                                // [32][64][2048] bf16 = 8MB
  unsigned short* fc1UT = (unsigned short*)p; p += (size_t)512 * 1024 * 2;
  unsigned short* fc1VT = (unsigned short*)p; p += (size_t)4096 * 512 * 2;
  unsigned short* fc2UT = (unsigned short*)p; p += (size_t)512 * 4096 * 2;
  unsigned short* fc2VT = (unsigned short*)p; p += (size_t)1024 * 512 * 2;

  const dim3 b256(256);
  const dim3 tb(32, 8);

  // weight prep
  concat_bias_k<<<12, b256, 0, stream>>>(qb, kb, vb, bqkv);
  wqkv_pre_k<<<dim3(16, 48), b256, 0, stream>>>(qU, qV, kU, kV, vU, vV, WqT_t1);
  tcvt_k<<<dim3(32, 24), tb, 0, stream>>>(outV, outVT, 768, 1024);
  cvt_k<<<768, b256, 0, stream>>>(outU, outUb, 1024 * 768);
  tcvt_k<<<dim3(16, 32), tb, 0, stream>>>(fc1U, fc1UT, 1024, 512);
  tcvt_k<<<dim3(128, 16), tb, 0, stream>>>(fc1V, fc1VT, 512, 4096);
  tcvt_k<<<dim3(16, 128), tb, 0, stream>>>(fc2U, fc2UT, 4096, 512);
  tcvt_k<<<dim3(32, 16), tb, 0, stream>>>(fc2V, fc2VT, 512, 1024);

  // attention path
  ln_k<<<4096, b256, 0, stream>>>(hidden, ln1g, ln1b, x1x2);
  gemm_k<128, 1, 1><<<dim3(24, 32), b256, 0, stream>>>(x1x2, WqT_t1, bqkv, nullptr, QKV, 4096, 3072, 1024);
  vtr_k<<<dim3(64, 2, 32), tb, 0, stream>>>(QKV, VT);
  gemm_k<128, 0, 1><<<dim3(8, 8), b256, 0, stream>>>(outVT, outUb, nullptr, nullptr, WoutT, 1024, 1024, 768);
  attn_k<<<dim3(32, 32), b256, 0, stream>>>(QKV, VT, ctxb);
  gemm_k<128, 3, 0><<<dim3(8, 32), b256, 0, stream>>>(ctxb, WoutT, outb, hidden, hbuf, 4096, 1024, 1024);

  // MLP path
  ln_k<<<4096, b256, 0, stream>>>(hbuf, ln2g, ln2b, x1x2);
  gemm_k<64, 0, 1><<<dim3(8, 32), b256, 0, stream>>>(x1x2, fc1UT, nullptr, nullptr, WqT_t1, 4096, 512, 1024);
  gemm_k<128, 2, 1><<<dim3(32, 32), b256, 0, stream>>>(WqT_t1, fc1VT, fc1b, nullptr, hmid, 4096, 4096, 512);
  gemm_k<64, 0, 1><<<dim3(8, 32), b256, 0, stream>>>(hmid, fc2UT, nullptr, nullptr, t2, 4096, 512, 4096);
  gemm_k<128, 3, 0><<<dim3(8, 32), b256, 0, stream>>>(t2, fc2VT, fc2b, hbuf, out, 4096, 1024, 512);
}

// Round 5
// 375.999 us; speedup vs baseline: 1.2975x; 1.2975x over previous
//
#include <hip/hip_runtime.h>
#include <hip/hip_bf16.h>

typedef float f32x4 __attribute__((ext_vector_type(4)));
typedef __bf16 bf16x8 __attribute__((ext_vector_type(8)));
typedef unsigned short u16x8 __attribute__((ext_vector_type(8)));
typedef unsigned short u16x4 __attribute__((ext_vector_type(4)));

#define QSCALE 0.180336881f  /* 0.125 * log2(e): folds attn scale + exp2 domain into Q */

__device__ __forceinline__ unsigned short f2bf(float f) {
  union { float f; unsigned int u; } v; v.f = f;
  return (unsigned short)((v.u + 0x7FFFu + ((v.u >> 16) & 1u)) >> 16);
}

__device__ __forceinline__ f32x4 mfma16(bf16x8 a, bf16x8 b, f32x4 c) {
  return __builtin_amdgcn_mfma_f32_16x16x32_bf16(a, b, c, 0, 0, 0);
}

__device__ __forceinline__ void gload16(const unsigned short* g, unsigned short* l) {
  __builtin_amdgcn_global_load_lds(
      (const __attribute__((address_space(1))) void*)g,
      (__attribute__((address_space(3))) void*)l, 16, 0, 0);
}

// ---------------- small utility kernels ----------------

__global__ void concat_bias_k(const float* __restrict__ qb, const float* __restrict__ kb,
                              const float* __restrict__ vb, float* __restrict__ out) {
  const int i = blockIdx.x * 256 + threadIdx.x;
  if (i >= 3072) return;
  const float* s = (i < 1024) ? qb : (i < 2048 ? kb : vb);
  out[i] = s[i & 1023] * (i < 1024 ? QSCALE : 1.0f);
}

// fp32 [R,C] -> bf16 [C,R]
__global__ void tcvt_k(const float* __restrict__ in, unsigned short* __restrict__ out,
                       int R, int C) {
  __shared__ float tile[32][33];
  const int x = blockIdx.x * 32 + threadIdx.x;
  const int y0 = blockIdx.y * 32;
#pragma unroll
  for (int i = 0; i < 32; i += 8)
    tile[threadIdx.y + i][threadIdx.x] = in[(size_t)(y0 + threadIdx.y + i) * C + x];
  __syncthreads();
  const int ox = y0 + threadIdx.x;
  const int oy0 = blockIdx.x * 32;
#pragma unroll
  for (int i = 0; i < 32; i += 8)
    out[(size_t)(oy0 + threadIdx.y + i) * R + ox] = f2bf(tile[threadIdx.x][threadIdx.y + i]);
}

__global__ void cvt_k(const float* __restrict__ in, unsigned short* __restrict__ out, int n) {
  const int i = (blockIdx.x * 256 + threadIdx.x) * 4;
  if (i >= n) return;
  const f32x4 v = *(const f32x4*)(in + i);
  u16x4 o;
#pragma unroll
  for (int k = 0; k < 4; ++k) o[k] = f2bf(v[k]);
  *(u16x4*)(out + i) = o;
}

// V-transpose: QKV[b][s][2048 + h*64 + d] -> VT[(b*16+h)][d][s]  (bf16)
__global__ void vtr_k(const unsigned short* __restrict__ QKV, unsigned short* __restrict__ VT) {
  __shared__ unsigned short tile[32][33];
  const int bh = blockIdx.z, b = bh >> 4, h = bh & 15;
  const int s0 = blockIdx.x * 32, d0 = blockIdx.y * 32;
  const unsigned short* src = QKV + (size_t)b * 2048 * 3072 + 2048 + h * 64;
#pragma unroll
  for (int i = 0; i < 32; i += 8)
    tile[threadIdx.y + i][threadIdx.x] = src[(size_t)(s0 + threadIdx.y + i) * 3072 + d0 + threadIdx.x];
  __syncthreads();
  unsigned short* dst = VT + (size_t)bh * 64 * 2048;
#pragma unroll
  for (int i = 0; i < 32; i += 8)
    dst[(size_t)(d0 + threadIdx.y + i) * 2048 + s0 + threadIdx.x] = tile[threadIdx.x][threadIdx.y + i];
}

// Wqkv^T[(m*1024 + h*64 + e)*1024 + d] = sum_r U_m[d,h,r] * V_m[h,r,e]  (Q part scaled)
__global__ __launch_bounds__(256) void wqkv_pre_k(
    const float* __restrict__ qU, const float* __restrict__ qV,
    const float* __restrict__ kU, const float* __restrict__ kV,
    const float* __restrict__ vU, const float* __restrict__ vV,
    unsigned short* __restrict__ WT) {
  __shared__ float Us[64][48];
  __shared__ float Vs[48][64];
  const int m = blockIdx.y >> 4, h = blockIdx.y & 15;
  const int d0 = blockIdx.x * 64;
  const float* U = (m == 0) ? qU : (m == 1 ? kU : vU);
  const float* V = (m == 0) ? qV : (m == 1 ? kV : vV);
  const float qs = (m == 0) ? QSCALE : 1.0f;
  const int t = threadIdx.x;
  for (int idx = t; idx < 64 * 48; idx += 256) {
    const int d = idx / 48, r = idx - d * 48;
    Us[d][r] = U[(size_t)(d0 + d) * 768 + h * 48 + r];
  }
  for (int idx = t; idx < 48 * 64; idx += 256) {
    const int r = idx >> 6, e = idx & 63;
    Vs[r][e] = V[(h * 48 + r) * 64 + e];
  }
  __syncthreads();
  const int e = t & 63, dg = t >> 6;
  for (int j = 0; j < 16; ++j) {
    const int d = dg * 16 + j;
    float s = 0.f;
#pragma unroll
    for (int r = 0; r < 48; ++r) s = fmaf(Us[d][r], Vs[r][e], s);
    WT[(size_t)(m * 1024 + h * 64 + e) * 1024 + d0 + d] = f2bf(s * qs);
  }
}

// LayerNorm over D=1024, fp32 in, bf16 out. One block per row.
__global__ __launch_bounds__(256) void ln_k(
    const float* __restrict__ in, const float* __restrict__ gw,
    const float* __restrict__ bw, unsigned short* __restrict__ out) {
  const int row = blockIdx.x, t = threadIdx.x;
  const f32x4 v = *(const f32x4*)(in + (size_t)row * 1024 + t * 4);
  float s = v[0] + v[1] + v[2] + v[3];
  float ss = v[0] * v[0] + v[1] * v[1] + v[2] * v[2] + v[3] * v[3];
#pragma unroll
  for (int off = 1; off < 64; off <<= 1) {
    s += __shfl_xor(s, off);
    ss += __shfl_xor(ss, off);
  }
  __shared__ float red[8];
  if ((t & 63) == 0) { red[(t >> 6) * 2] = s; red[(t >> 6) * 2 + 1] = ss; }
  __syncthreads();
  s = red[0] + red[2] + red[4] + red[6];
  ss = red[1] + red[3] + red[5] + red[7];
  const float mean = s * (1.0f / 1024.0f);
  const float rstd = rsqrtf(ss * (1.0f / 1024.0f) - mean * mean + 1e-5f);
  const f32x4 g4 = *(const f32x4*)(gw + t * 4);
  const f32x4 b4 = *(const f32x4*)(bw + t * 4);
  u16x4 o;
#pragma unroll
  for (int i = 0; i < 4; ++i) o[i] = f2bf((v[i] - mean) * rstd * g4[i] + b4[i]);
  *(u16x4*)(out + (size_t)row * 1024 + t * 4) = o;
}

// ---------------- generic bf16 MFMA GEMM (double-buffered global_load_lds) ----------------
template <int BN, int EPI, int OUTBF>
__global__ __launch_bounds__(256) void gemm_k(
    const unsigned short* __restrict__ A, const unsigned short* __restrict__ Bt,
    const float* __restrict__ bias, const float* __restrict__ resid,
    void* __restrict__ Cout, int M, int N, int K) {
  constexpr int FN = BN / 32;
  __shared__ unsigned short As[2][128 * 32];
  __shared__ unsigned short Bs[2][BN * 32];
  const int t = threadIdx.x;
  const int lane = t & 63, wid = t >> 6;
  const int m0 = blockIdx.y * 128, n0 = blockIdx.x * BN;
  const int wm = (wid >> 1) * 64, wn = (wid & 1) * (BN / 2);
  const int fr = lane & 15, fg = (lane >> 4) * 8;

  f32x4 acc[4][FN];
#pragma unroll
  for (int i = 0; i < 4; ++i)
#pragma unroll
    for (int j = 0; j < FN; ++j) acc[i][j] = (f32x4){0.f, 0.f, 0.f, 0.f};

  const int sub = lane >> 2, c8 = (lane & 3) * 8;
  const int loff = wid * 512 + sub * 32 + c8;
  const unsigned short* Ag0 = A + (size_t)(m0 + wid * 16 + sub) * K + c8;
  const unsigned short* Ag1 = A + (size_t)(m0 + (wid + 4) * 16 + sub) * K + c8;
  const unsigned short* Bg0 = Bt + (size_t)(n0 + wid * 16 + sub) * K + c8;
  const unsigned short* Bg1 = Bt + (size_t)(n0 + ((wid + 4) & (BN / 16 - 1)) * 16 + sub) * K + c8;

  const int nk = K >> 5;
  gload16(Ag0, &As[0][loff]);
  gload16(Ag1, &As[0][loff + 2048]);
  gload16(Bg0, &Bs[0][loff]);
  if (BN == 128) gload16(Bg1, &Bs[0][loff + 2048]);

  for (int kt = 0; kt < nk; ++kt) {
    const int cur = kt & 1;
    __syncthreads();
    if (kt + 1 < nk) {
      const int ke = (kt + 1) * 32;
      gload16(Ag0 + ke, &As[cur ^ 1][loff]);
      gload16(Ag1 + ke, &As[cur ^ 1][loff + 2048]);
      gload16(Bg0 + ke, &Bs[cur ^ 1][loff]);
      if (BN == 128) gload16(Bg1 + ke, &Bs[cur ^ 1][loff + 2048]);
    }
    bf16x8 af[4], bfr[FN];
#pragma unroll
    for (int i = 0; i < 4; ++i) af[i] = *(const bf16x8*)&As[cur][(wm + i * 16 + fr) * 32 + fg];
#pragma unroll
    for (int j = 0; j < FN; ++j) bfr[j] = *(const bf16x8*)&Bs[cur][(wn + j * 16 + fr) * 32 + fg];
#pragma unroll
    for (int i = 0; i < 4; ++i)
#pragma unroll
      for (int j = 0; j < FN; ++j) acc[i][j] = mfma16(af[i], bfr[j], acc[i][j]);
  }

#pragma unroll
  for (int j = 0; j < FN; ++j) {
    const int col = n0 + wn + j * 16 + fr;
    const float bval = (EPI >= 1) ? bias[col] : 0.0f;
#pragma unroll
    for (int i = 0; i < 4; ++i) {
#pragma unroll
      for (int r = 0; r < 4; ++r) {
        const int row = m0 + wm + i * 16 + ((lane >> 4) << 2) + r;
        float v = acc[i][j][r] + bval;
        if (EPI == 2) {  // gelu tanh-approx: v * sigmoid(2z)
          const float z = 0.7978845608028654f * (v + 0.044715f * v * v * v);
          v = v - v / (__expf(2.0f * z) + 1.0f);
        }
        if (EPI == 3) v += resid[(size_t)row * N + col];
        if (OUTBF)
          ((unsigned short*)Cout)[(size_t)row * N + col] = f2bf(v);
        else
          ((float*)Cout)[(size_t)row * N + col] = v;
      }
    }
  }
}

// ---------------- causal flash attention ----------------
// Staged K/V, double-buffered via global_load_lds with XOR-swizzled source cols
// (LDS linear for the DMA; swizzle applied on the global address and on ds_read).
// Q pre-scaled by 0.125*log2e (exp2 domain); row-sum via ones-fragment MFMA.
// grid (32,32): qt = 31-bx (LPT order), 4 waves, wave w owns q rows qt*64+16w..+15.
// LDS: 2*8KB (K) + 2*8KB (V) + 8KB (Ps) = 40960 B -> 4 blocks/CU.
__global__ __launch_bounds__(256) void attn_k(
    const unsigned short* __restrict__ QKV, const unsigned short* __restrict__ VT,
    unsigned short* __restrict__ ctx) {
  __shared__ unsigned short Ks[2][64 * 64];
  __shared__ unsigned short Vs[2][64 * 64];
  __shared__ __bf16 Ps[4][16][64];  // chunk-swizzled: chunk stored at (chunk ^ (qrow&7))
  const int qt = 31 - blockIdx.x, bh = blockIdx.y;
  const int b = bh >> 4, h = bh & 15;
  const int t = threadIdx.x, lane = t & 63, w = t >> 6;
  const int g = lane >> 4, c = lane & 15;
  const int cks = c & 7;
  const int q0 = qt * 64;
  const size_t base = (size_t)b * 2048 * 3072;

  const unsigned short* qp = QKV + base + (size_t)(q0 + w * 16 + c) * 3072 + h * 64 + g * 8;
  const bf16x8 qf0 = *(const bf16x8*)qp;
  const bf16x8 qf1 = *(const bf16x8*)(qp + 32);

  bf16x8 onef;
#pragma unroll
  for (int i = 0; i < 8; ++i) onef[i] = (__bf16)1.0f;

  // staging: thread t covers tile rows r0, r0+32; stored chunk ch holds source chunk ch^(r0&7)
  const int r0 = t >> 3, ch = t & 7;
  const int chs = ch ^ (r0 & 7);
  const unsigned short* KgA = QKV + base + 1024 + h * 64 + (size_t)r0 * 3072 + chs * 8;
  const unsigned short* VgA = VT + ((size_t)bh * 64 + r0) * 2048 + chs * 8;
  const int l0 = t * 8;  // LDS elems: lane-linear 16B chunks

  f32x4 o[4];
#pragma unroll
  for (int d = 0; d < 4; ++d) o[d] = (f32x4){0.f, 0.f, 0.f, 0.f};
  f32x4 ol = (f32x4){0.f, 0.f, 0.f, 0.f};
  float mrow[4];
#pragma unroll
  for (int r = 0; r < 4; ++r) mrow[r] = -1e30f;

#define ATTN_STAGE(buf, kt_)                                      \
  {                                                               \
    const size_t ko = (size_t)(kt_) * 64 * 3072;                  \
    const int vo = (kt_) * 64;                                    \
    gload16(KgA + ko, &Ks[buf][l0]);                              \
    gload16(KgA + ko + (size_t)32 * 3072, &Ks[buf][l0 + 2048]);   \
    gload16(VgA + vo, &Vs[buf][l0]);                              \
    gload16(VgA + vo + (size_t)32 * 2048, &Vs[buf][l0 + 2048]);   \
  }

  ATTN_STAGE(0, 0);
  __syncthreads();

  for (int kt = 0; kt <= qt; ++kt) {
    const int cur = kt & 1;
    if (kt < qt) ATTN_STAGE(cur ^ 1, kt + 1);

    // S = Q K^T (exp2 domain). C layout: col=key=c, row=q=4g+r
    f32x4 s4[4];
    __builtin_amdgcn_s_setprio(1);
#pragma unroll
    for (int t16 = 0; t16 < 4; ++t16) {
      const int krow = (t16 * 16 + c) * 64;
      const bf16x8 kf0 = *(const bf16x8*)&Ks[cur][krow + ((g ^ cks) * 8)];
      const bf16x8 kf1 = *(const bf16x8*)&Ks[cur][krow + (((4 + g) ^ cks) * 8)];
      f32x4 a = (f32x4){0.f, 0.f, 0.f, 0.f};
      a = mfma16(qf0, kf0, a);
      a = mfma16(qf1, kf1, a);
      s4[t16] = a;
    }
    __builtin_amdgcn_s_setprio(0);
    if (kt == qt) {  // diagonal tile: causal mask
      const int qbase = q0 + w * 16 + g * 4;
      const int kbase = kt * 64 + c;
#pragma unroll
      for (int t16 = 0; t16 < 4; ++t16)
#pragma unroll
        for (int r = 0; r < 4; ++r)
          if (kbase + t16 * 16 > qbase + r) s4[t16][r] = -1e30f;
    }
    // online softmax: max over 16 key-lanes
    float mx[4];
#pragma unroll
    for (int r = 0; r < 4; ++r)
      mx[r] = fmaxf(fmaxf(s4[0][r], s4[1][r]), fmaxf(s4[2][r], s4[3][r]));
#pragma unroll
    for (int off = 1; off < 16; off <<= 1)
#pragma unroll
      for (int r = 0; r < 4; ++r) mx[r] = fmaxf(mx[r], __shfl_xor(mx[r], off));
    float fac[4];
#pragma unroll
    for (int r = 0; r < 4; ++r) {
      const float mn = fmaxf(mrow[r], mx[r]);
      fac[r] = exp2f(mrow[r] - mn);
      mrow[r] = mn;
    }
#pragma unroll
    for (int t16 = 0; t16 < 4; ++t16)
#pragma unroll
      for (int r = 0; r < 4; ++r) {
        const int q = g * 4 + r;
        const int col = (((t16 * 2 + (c >> 3)) ^ (q & 7)) * 8) + cks;
        Ps[w][q][col] = (__bf16)exp2f(s4[t16][r] - mrow[r]);
      }
#pragma unroll
    for (int d = 0; d < 4; ++d)
#pragma unroll
      for (int r = 0; r < 4; ++r) o[d][r] *= fac[r];
#pragma unroll
    for (int r = 0; r < 4; ++r) ol[r] *= fac[r];
    // O += P V ; l += P @ ones
    __builtin_amdgcn_s_setprio(1);
#pragma unroll
    for (int ks = 0; ks < 2; ++ks) {
      const bf16x8 pf = *(const bf16x8*)&Ps[w][c][((ks * 4 + g) ^ cks) * 8];
#pragma unroll
      for (int d = 0; d < 4; ++d) {
        const bf16x8 vf = *(const bf16x8*)&Vs[cur][(d * 16 + c) * 64 + (((ks * 4 + g) ^ cks) * 8)];
        o[d] = mfma16(pf, vf, o[d]);
      }
      ol = mfma16(pf, onef, ol);
    }
    __builtin_amdgcn_s_setprio(0);
    __syncthreads();  // drains vmcnt: next tile staged; buf[cur] reads done
  }
#pragma unroll
  for (int d = 0; d < 4; ++d)
#pragma unroll
    for (int r = 0; r < 4; ++r) {
      const float v = o[d][r] / ol[r];
      ctx[(size_t)(b * 2048 + q0 + w * 16 + g * 4 + r) * 1024 + h * 64 + d * 16 + c] = f2bf(v);
    }
#undef ATTN_STAGE
}

// ---------------- launch ----------------

extern "C" void kernel_launch(void* const* d_in, const int* in_sizes, int n_in,
                              void* d_out, int out_size, void* d_ws, size_t ws_size,
                              hipStream_t stream) {
  const float* hidden = (const float*)d_in[0];
  const float* ln1g = (const float*)d_in[1];
  const float* ln1b = (const float*)d_in[2];
  const float* ln2g = (const float*)d_in[3];
  const float* ln2b = (const float*)d_in[4];
  const float* qU = (const float*)d_in[5];
  const float* qV = (const float*)d_in[6];
  const float* qb = (const float*)d_in[7];
  const float* kU = (const float*)d_in[8];
  const float* kV = (const float*)d_in[9];
  const float* kb = (const float*)d_in[10];
  const float* vU = (const float*)d_in[11];
  const float* vV = (const float*)d_in[12];
  const float* vb = (const float*)d_in[13];
  const float* outU = (const float*)d_in[14];
  const float* outV = (const float*)d_in[15];
  const float* outb = (const float*)d_in[16];
  const float* fc1U = (const float*)d_in[17];
  const float* fc1V = (const float*)d_in[18];
  const float* fc1b = (const float*)d_in[19];
  const float* fc2U = (const float*)d_in[20];
  const float* fc2V = (const float*)d_in[21];
  const float* fc2b = (const float*)d_in[22];
  float* out = (float*)d_out;

  // workspace carve, lifetime-based aliasing
  char* p = (char*)d_ws;
  unsigned short* x1x2 = (unsigned short*)p; p += (size_t)4096 * 1024 * 2;   // x1 (LN1), later x2 (LN2)
  unsigned short* WqT_t1 = (unsigned short*)p; p += (size_t)3072 * 1024 * 2; // Wqkv^T, later t1
  float* bqkv = (float*)p; p += 3072 * 4;
  char* bigA = p; p += (size_t)4096 * 3072 * 2 + (size_t)4096 * 1024 * 2;    // QKV + ctx, later hmid
  unsigned short* QKV = (unsigned short*)bigA;
  unsigned short* ctxb = (unsigned short*)(bigA + (size_t)4096 * 3072 * 2);
  unsigned short* hmid = (unsigned short*)bigA;
  char* wo = p; p += (size_t)1024 * 768 * 2 * 2 + (size_t)1024 * 1024 * 2;   // outU,outV^T,Wout^T, later t2
  unsigned short* outUb = (unsigned short*)wo;
  unsigned short* outVT = (unsigned short*)(wo + (size_t)1024 * 768 * 2);
  unsigned short* WoutT = (unsigned short*)(wo + (size_t)1024 * 768 * 2 * 2);
  unsigned short* t2 = (unsigned short*)wo;
  float* hbuf = (float*)p; p += (size_t)4096 * 1024 * 4;                     // h (fp32 residual); VT aliases pre-attn
  unsigned short* VT = (unsigned short*)hbuf;                                // [32][64][2048] bf16 = 8MB
  unsigned short* fc1UT = (unsigned short*)p; p += (size_t)512 * 1024 * 2;
  unsigned short* fc1VT = (unsigned short*)p; p += (size_t)4096 * 512 * 2;
  unsigned short* fc2UT = (unsigned short*)p; p += (size_t)512 * 4096 * 2;
  unsigned short* fc2VT = (unsigned short*)p; p += (size_t)1024 * 512 * 2;

  const dim3 b256(256);
  const dim3 tb(32, 8);

  // weight prep
  concat_bias_k<<<12, b256, 0, stream>>>(qb, kb, vb, bqkv);
  wqkv_pre_k<<<dim3(16, 48), b256, 0, stream>>>(qU, qV, kU, kV, vU, vV, WqT_t1);
  tcvt_k<<<dim3(32, 24), tb, 0, stream>>>(outV, outVT, 768, 1024);
  cvt_k<<<768, b256, 0, stream>>>(outU, outUb, 1024 * 768);
  tcvt_k<<<dim3(16, 32), tb, 0, stream>>>(fc1U, fc1UT, 1024, 512);
  tcvt_k<<<dim3(128, 16), tb, 0, stream>>>(fc1V, fc1VT, 512, 4096);
  tcvt_k<<<dim3(16, 128), tb, 0, stream>>>(fc2U, fc2UT, 4096, 512);
  tcvt_k<<<dim3(32, 16), tb, 0, stream>>>(fc2V, fc2VT, 512, 1024);

  // attention path
  ln_k<<<4096, b256, 0, stream>>>(hidden, ln1g, ln1b, x1x2);
  gemm_k<128, 1, 1><<<dim3(24, 32), b256, 0, stream>>>(x1x2, WqT_t1, bqkv, nullptr, QKV, 4096, 3072, 1024);
  vtr_k<<<dim3(64, 2, 32), tb, 0, stream>>>(QKV, VT);
  gemm_k<128, 0, 1><<<dim3(8, 8), b256, 0, stream>>>(outVT, outUb, nullptr, nullptr, WoutT, 1024, 1024, 768);
  attn_k<<<dim3(32, 32), b256, 0, stream>>>(QKV, VT, ctxb);
  gemm_k<128, 3, 0><<<dim3(8, 32), b256, 0, stream>>>(ctxb, WoutT, outb, hidden, hbuf, 4096, 1024, 1024);

  // MLP path
  ln_k<<<4096, b256, 0, stream>>>(hbuf, ln2g, ln2b, x1x2);
  gemm_k<64, 0, 1><<<dim3(8, 32), b256, 0, stream>>>(x1x2, fc1UT, nullptr, nullptr, WqT_t1, 4096, 512, 1024);
  gemm_k<128, 2, 1><<<dim3(32, 32), b256, 0, stream>>>(WqT_t1, fc1VT, fc1b, nullptr, hmid, 4096, 4096, 512);
  gemm_k<64, 0, 1><<<dim3(8, 32), b256, 0, stream>>>(hmid, fc2UT, nullptr, nullptr, t2, 4096, 512, 4096);
  gemm_k<128, 3, 0><<<dim3(8, 32), b256, 0, stream>>>(t2, fc2VT, fc2b, hbuf, out, 4096, 1024, 512);
}

// Round 6
// 319.436 us; speedup vs baseline: 1.5273x; 1.1771x over previous
//
#include <hip/hip_runtime.h>
#include <hip/hip_bf16.h>

typedef float f32x4 __attribute__((ext_vector_type(4)));
typedef __bf16 bf16x8 __attribute__((ext_vector_type(8)));
typedef unsigned short u16x8 __attribute__((ext_vector_type(8)));
typedef unsigned short u16x4 __attribute__((ext_vector_type(4)));

#define QSCALE 0.180336881f  /* 0.125 * log2(e): folds attn scale + exp2 domain into Q */

__device__ __forceinline__ unsigned short f2bf(float f) {
  union { float f; unsigned int u; } v; v.f = f;
  return (unsigned short)((v.u + 0x7FFFu + ((v.u >> 16) & 1u)) >> 16);
}

__device__ __forceinline__ f32x4 mfma16(bf16x8 a, bf16x8 b, f32x4 c) {
  return __builtin_amdgcn_mfma_f32_16x16x32_bf16(a, b, c, 0, 0, 0);
}

__device__ __forceinline__ void gload16(const unsigned short* g, unsigned short* l) {
  __builtin_amdgcn_global_load_lds(
      (const __attribute__((address_space(1))) void*)g,
      (__attribute__((address_space(3))) void*)l, 16, 0, 0);
}

// ---------------- small utility kernels ----------------

__global__ void concat_bias_k(const float* __restrict__ qb, const float* __restrict__ kb,
                              const float* __restrict__ vb, float* __restrict__ out) {
  const int i = blockIdx.x * 256 + threadIdx.x;
  if (i >= 3072) return;
  const float* s = (i < 1024) ? qb : (i < 2048 ? kb : vb);
  out[i] = s[i & 1023] * (i < 1024 ? QSCALE : 1.0f);
}

// fp32 [R,C] -> bf16 [C,R]
__global__ void tcvt_k(const float* __restrict__ in, unsigned short* __restrict__ out,
                       int R, int C) {
  __shared__ float tile[32][33];
  const int x = blockIdx.x * 32 + threadIdx.x;
  const int y0 = blockIdx.y * 32;
#pragma unroll
  for (int i = 0; i < 32; i += 8)
    tile[threadIdx.y + i][threadIdx.x] = in[(size_t)(y0 + threadIdx.y + i) * C + x];
  __syncthreads();
  const int ox = y0 + threadIdx.x;
  const int oy0 = blockIdx.x * 32;
#pragma unroll
  for (int i = 0; i < 32; i += 8)
    out[(size_t)(oy0 + threadIdx.y + i) * R + ox] = f2bf(tile[threadIdx.x][threadIdx.y + i]);
}

__global__ void cvt_k(const float* __restrict__ in, unsigned short* __restrict__ out, int n) {
  const int i = (blockIdx.x * 256 + threadIdx.x) * 4;
  if (i >= n) return;
  const f32x4 v = *(const f32x4*)(in + i);
  u16x4 o;
#pragma unroll
  for (int k = 0; k < 4; ++k) o[k] = f2bf(v[k]);
  *(u16x4*)(out + i) = o;
}

// V-transpose: QKV[b][s][2048 + h*64 + d] -> VT[(b*16+h)][d][s]  (bf16)
__global__ void vtr_k(const unsigned short* __restrict__ QKV, unsigned short* __restrict__ VT) {
  __shared__ unsigned short tile[32][33];
  const int bh = blockIdx.z, b = bh >> 4, h = bh & 15;
  const int s0 = blockIdx.x * 32, d0 = blockIdx.y * 32;
  const unsigned short* src = QKV + (size_t)b * 2048 * 3072 + 2048 + h * 64;
#pragma unroll
  for (int i = 0; i < 32; i += 8)
    tile[threadIdx.y + i][threadIdx.x] = src[(size_t)(s0 + threadIdx.y + i) * 3072 + d0 + threadIdx.x];
  __syncthreads();
  unsigned short* dst = VT + (size_t)bh * 64 * 2048;
#pragma unroll
  for (int i = 0; i < 32; i += 8)
    dst[(size_t)(d0 + threadIdx.y + i) * 2048 + s0 + threadIdx.x] = tile[threadIdx.x][threadIdx.y + i];
}

// Wqkv^T[(m*1024 + h*64 + e)*1024 + d] = sum_r U_m[d,h,r] * V_m[h,r,e]  (Q part scaled)
__global__ __launch_bounds__(256) void wqkv_pre_k(
    const float* __restrict__ qU, const float* __restrict__ qV,
    const float* __restrict__ kU, const float* __restrict__ kV,
    const float* __restrict__ vU, const float* __restrict__ vV,
    unsigned short* __restrict__ WT) {
  __shared__ float Us[64][48];
  __shared__ float Vs[48][64];
  const int m = blockIdx.y >> 4, h = blockIdx.y & 15;
  const int d0 = blockIdx.x * 64;
  const float* U = (m == 0) ? qU : (m == 1 ? kU : vU);
  const float* V = (m == 0) ? qV : (m == 1 ? kV : vV);
  const float qs = (m == 0) ? QSCALE : 1.0f;
  const int t = threadIdx.x;
  for (int idx = t; idx < 64 * 48; idx += 256) {
    const int d = idx / 48, r = idx - d * 48;
    Us[d][r] = U[(size_t)(d0 + d) * 768 + h * 48 + r];
  }
  for (int idx = t; idx < 48 * 64; idx += 256) {
    const int r = idx >> 6, e = idx & 63;
    Vs[r][e] = V[(h * 48 + r) * 64 + e];
  }
  __syncthreads();
  const int e = t & 63, dg = t >> 6;
  for (int j = 0; j < 16; ++j) {
    const int d = dg * 16 + j;
    float s = 0.f;
#pragma unroll
    for (int r = 0; r < 48; ++r) s = fmaf(Us[d][r], Vs[r][e], s);
    WT[(size_t)(m * 1024 + h * 64 + e) * 1024 + d0 + d] = f2bf(s * qs);
  }
}

// LayerNorm over D=1024, fp32 in, bf16 out. One block per row.
__global__ __launch_bounds__(256) void ln_k(
    const float* __restrict__ in, const float* __restrict__ gw,
    const float* __restrict__ bw, unsigned short* __restrict__ out) {
  const int row = blockIdx.x, t = threadIdx.x;
  const f32x4 v = *(const f32x4*)(in + (size_t)row * 1024 + t * 4);
  float s = v[0] + v[1] + v[2] + v[3];
  float ss = v[0] * v[0] + v[1] * v[1] + v[2] * v[2] + v[3] * v[3];
#pragma unroll
  for (int off = 1; off < 64; off <<= 1) {
    s += __shfl_xor(s, off);
    ss += __shfl_xor(ss, off);
  }
  __shared__ float red[8];
  if ((t & 63) == 0) { red[(t >> 6) * 2] = s; red[(t >> 6) * 2 + 1] = ss; }
  __syncthreads();
  s = red[0] + red[2] + red[4] + red[6];
  ss = red[1] + red[3] + red[5] + red[7];
  const float mean = s * (1.0f / 1024.0f);
  const float rstd = rsqrtf(ss * (1.0f / 1024.0f) - mean * mean + 1e-5f);
  const f32x4 g4 = *(const f32x4*)(gw + t * 4);
  const f32x4 b4 = *(const f32x4*)(bw + t * 4);
  u16x4 o;
#pragma unroll
  for (int i = 0; i < 4; ++i) o[i] = f2bf((v[i] - mean) * rstd * g4[i] + b4[i]);
  *(u16x4*)(out + (size_t)row * 1024 + t * 4) = o;
}

// ---------------- generic bf16 MFMA GEMM (double-buffered global_load_lds) ----------------
// C[M,N] = A[M,K] @ Bt[N,K]^T. BM in {64,128}, BN in {64,128}. 256 threads = 4 waves
// (2x2), wave tile (BM/2)x(BN/2), 16x16x32 MFMA. One barrier per K-step (BK=32).
template <int BM, int BN, int EPI, int OUTBF>
__global__ __launch_bounds__(256) void gemm_k(
    const unsigned short* __restrict__ A, const unsigned short* __restrict__ Bt,
    const float* __restrict__ bias, const float* __restrict__ resid,
    void* __restrict__ Cout, int M, int N, int K) {
  constexpr int MI = BM / 32;
  constexpr int FN = BN / 32;
  __shared__ unsigned short As[2][BM * 32];
  __shared__ unsigned short Bs[2][BN * 32];
  const int t = threadIdx.x;
  const int lane = t & 63, wid = t >> 6;
  const int m0 = blockIdx.y * BM, n0 = blockIdx.x * BN;
  const int wm = (wid >> 1) * (BM / 2), wn = (wid & 1) * (BN / 2);
  const int fr = lane & 15, fg = (lane >> 4) * 8;

  f32x4 acc[MI][FN];
#pragma unroll
  for (int i = 0; i < MI; ++i)
#pragma unroll
    for (int j = 0; j < FN; ++j) acc[i][j] = (f32x4){0.f, 0.f, 0.f, 0.f};

  // staging: chunk q -> row q>>2, col (q&3)*8, lds elem 8q; thread t covers q = t (+256 if 128-row tile)
  const unsigned short* Ag0 = A + (size_t)(m0 + (t >> 2)) * K + (t & 3) * 8;
  const unsigned short* Ag1 = A + (size_t)(m0 + 64 + (t >> 2)) * K + (t & 3) * 8;
  const unsigned short* Bg0 = Bt + (size_t)(n0 + (t >> 2)) * K + (t & 3) * 8;
  const unsigned short* Bg1 = Bt + (size_t)(n0 + 64 + (t >> 2)) * K + (t & 3) * 8;
  const int l0 = t * 8;

#define GEMM_STAGE(buf, ke)                                   \
  {                                                           \
    gload16(Ag0 + (ke), &As[buf][l0]);                        \
    if (BM == 128) gload16(Ag1 + (ke), &As[buf][l0 + 2048]);  \
    gload16(Bg0 + (ke), &Bs[buf][l0]);                        \
    if (BN == 128) gload16(Bg1 + (ke), &Bs[buf][l0 + 2048]);  \
  }

  const int nk = K >> 5;
  GEMM_STAGE(0, 0);

  for (int kt = 0; kt < nk; ++kt) {
    const int cur = kt & 1;
    __syncthreads();
    if (kt + 1 < nk) GEMM_STAGE(cur ^ 1, (kt + 1) * 32);
    bf16x8 af[MI], bfr[FN];
#pragma unroll
    for (int i = 0; i < MI; ++i) af[i] = *(const bf16x8*)&As[cur][(wm + i * 16 + fr) * 32 + fg];
#pragma unroll
    for (int j = 0; j < FN; ++j) bfr[j] = *(const bf16x8*)&Bs[cur][(wn + j * 16 + fr) * 32 + fg];
#pragma unroll
    for (int i = 0; i < MI; ++i)
#pragma unroll
      for (int j = 0; j < FN; ++j) acc[i][j] = mfma16(af[i], bfr[j], acc[i][j]);
  }
#undef GEMM_STAGE

#pragma unroll
  for (int j = 0; j < FN; ++j) {
    const int col = n0 + wn + j * 16 + fr;
    const float bval = (EPI >= 1) ? bias[col] : 0.0f;
#pragma unroll
    for (int i = 0; i < MI; ++i) {
#pragma unroll
      for (int r = 0; r < 4; ++r) {
        const int row = m0 + wm + i * 16 + ((lane >> 4) << 2) + r;
        float v = acc[i][j][r] + bval;
        if (EPI == 2) {  // gelu tanh-approx: v * sigmoid(2z)
          const float z = 0.7978845608028654f * (v + 0.044715f * v * v * v);
          v = v - v / (__expf(2.0f * z) + 1.0f);
        }
        if (EPI == 3) v += resid[(size_t)row * N + col];
        if (OUTBF)
          ((unsigned short*)Cout)[(size_t)row * N + col] = f2bf(v);
        else
          ((float*)Cout)[(size_t)row * N + col] = v;
      }
    }
  }
}

// ---------------- causal flash attention ----------------
// Reg-staged K/V -> swizzled LDS, 3-buffer pipeline with 2 tiles of prefetch in
// flight; ONE barrier per iter, no vmcnt drain (vmcnt waits sit at the ds_write
// consuming the regs, ~1.5 iters after issue). Q pre-scaled by 0.125*log2e
// (exp2 domain); row-sum via ones-fragment MFMA. grid (16,32): block p handles
// q-tiles {p, 31-p} (uniform 33 iters). LDS 56KB -> 2 blocks/CU.
__global__ __launch_bounds__(256) void attn_k(
    const unsigned short* __restrict__ QKV, const unsigned short* __restrict__ VT,
    unsigned short* __restrict__ ctx) {
  __shared__ unsigned short Ks[3][64 * 64];
  __shared__ unsigned short Vs[3][64 * 64];
  __shared__ __bf16 Ps[4][16][64];  // chunk-swizzled: source chunk s stored at s^(row&7)
  const int p = blockIdx.x, bh = blockIdx.y;
  const int b = bh >> 4, h = bh & 15;
  const int t = threadIdx.x, lane = t & 63, w = t >> 6;
  const int g = lane >> 4, c = lane & 15;
  const int cks = c & 7;
  const size_t base = (size_t)b * 2048 * 3072;

  // staging geometry: thread t covers tile row r0 = t>>2, source chunks ch0, ch0+1
  const int r0 = t >> 2;
  const int ch0 = (t & 3) * 2;
  const int lw0 = r0 * 64 + ((ch0 ^ (r0 & 7)) * 8);
  const int lw1 = r0 * 64 + (((ch0 + 1) ^ (r0 & 7)) * 8);
  const unsigned short* Kg = QKV + base + 1024 + h * 64 + (size_t)r0 * 3072 + ch0 * 8;
  const unsigned short* Vg = VT + ((size_t)bh * 64 + r0) * 2048 + ch0 * 8;

  // loop-invariant read offsets (swizzled)
  const int kro0 = (g ^ cks) * 8, kro1 = ((4 + g) ^ cks) * 8;
  const int pro0 = (g ^ cks) * 8, pro1 = ((4 + g) ^ cks) * 8;

  bf16x8 onef;
#pragma unroll
  for (int i = 0; i < 8; ++i) onef[i] = (__bf16)1.0f;

  u16x8 ka0, ka1, va0, va1;  // reg set A (even tiles)
  u16x8 kb0, kb1, vb0, vb1;  // reg set B (odd tiles)

#define ATTN_LOAD(kt_, k0, k1, v0, v1)                      \
  {                                                         \
    const size_t ko = (size_t)(kt_) * 64 * 3072;            \
    const int vo = (kt_) * 64;                              \
    k0 = *(const u16x8*)(Kg + ko);                          \
    k1 = *(const u16x8*)(Kg + ko + 8);                      \
    v0 = *(const u16x8*)(Vg + vo);                          \
    v1 = *(const u16x8*)(Vg + vo + 8);                      \
  }
#define ATTN_WRITE(buf, k0, k1, v0, v1)                     \
  {                                                         \
    *(u16x8*)&Ks[buf][lw0] = k0;                            \
    *(u16x8*)&Ks[buf][lw1] = k1;                            \
    *(u16x8*)&Vs[buf][lw0] = v0;                            \
    *(u16x8*)&Vs[buf][lw1] = v1;                            \
  }

  for (int ph = 0; ph < 2; ++ph) {
    const int qt = ph ? (31 - p) : p;
    const int nt = qt + 1;
    const int q0 = qt * 64;

    const unsigned short* qp = QKV + base + (size_t)(q0 + w * 16 + c) * 3072 + h * 64 + g * 8;
    const bf16x8 qf0 = *(const bf16x8*)qp;
    const bf16x8 qf1 = *(const bf16x8*)(qp + 32);

    f32x4 o[4];
#pragma unroll
    for (int d = 0; d < 4; ++d) o[d] = (f32x4){0.f, 0.f, 0.f, 0.f};
    f32x4 ol = (f32x4){0.f, 0.f, 0.f, 0.f};
    float mrow[4];
#pragma unroll
    for (int r = 0; r < 4; ++r) mrow[r] = -1e30f;

    __syncthreads();  // prior phase's reads of all buffers complete
    ATTN_LOAD(0, ka0, ka1, va0, va1);
    ATTN_WRITE(0, ka0, ka1, va0, va1);
    if (nt > 1) ATTN_LOAD(1, kb0, kb1, vb0, vb1);

    int cur = 0, nx1 = 1;
    for (int j = 0; j < nt; ++j) {
      // write tile j+1 to LDS, then issue loads for tile j+2 into the freed set
      if (j + 1 < nt) {
        if ((j & 1) == 0) ATTN_WRITE(nx1, kb0, kb1, vb0, vb1)
        else ATTN_WRITE(nx1, ka0, ka1, va0, va1)
      }
      if (j + 2 < nt) {
        if ((j & 1) == 0) ATTN_LOAD(j + 2, ka0, ka1, va0, va1)
        else ATTN_LOAD(j + 2, kb0, kb1, vb0, vb1)
      }
      __syncthreads();

      // S = Q K^T (exp2 domain). C layout: col=key=c, row=q=4g+r
      f32x4 s4[4];
      __builtin_amdgcn_s_setprio(1);
#pragma unroll
      for (int t16 = 0; t16 < 4; ++t16) {
        const int krow = (t16 * 16 + c) * 64;
        const bf16x8 kf0 = *(const bf16x8*)&Ks[cur][krow + kro0];
        const bf16x8 kf1 = *(const bf16x8*)&Ks[cur][krow + kro1];
        f32x4 a = (f32x4){0.f, 0.f, 0.f, 0.f};
        a = mfma16(qf0, kf0, a);
        a = mfma16(qf1, kf1, a);
        s4[t16] = a;
      }
      __builtin_amdgcn_s_setprio(0);
      if (j == qt) {  // diagonal tile: causal mask
        const int qbase = q0 + w * 16 + g * 4;
        const int kbase = j * 64 + c;
#pragma unroll
        for (int t16 = 0; t16 < 4; ++t16)
#pragma unroll
          for (int r = 0; r < 4; ++r)
            if (kbase + t16 * 16 > qbase + r) s4[t16][r] = -1e30f;
      }
      // online softmax: max over 16 key-lanes
      float mx[4];
#pragma unroll
      for (int r = 0; r < 4; ++r)
        mx[r] = fmaxf(fmaxf(s4[0][r], s4[1][r]), fmaxf(s4[2][r], s4[3][r]));
#pragma unroll
      for (int off = 1; off < 16; off <<= 1)
#pragma unroll
        for (int r = 0; r < 4; ++r) mx[r] = fmaxf(mx[r], __shfl_xor(mx[r], off));
      float fac[4];
#pragma unroll
      for (int r = 0; r < 4; ++r) {
        const float mn = fmaxf(mrow[r], mx[r]);
        fac[r] = exp2f(mrow[r] - mn);
        mrow[r] = mn;
      }
#pragma unroll
      for (int t16 = 0; t16 < 4; ++t16)
#pragma unroll
        for (int r = 0; r < 4; ++r) {
          const int q = g * 4 + r;
          const int col = (((t16 * 2 + (c >> 3)) ^ (q & 7)) * 8) + cks;
          Ps[w][q][col] = (__bf16)exp2f(s4[t16][r] - mrow[r]);
        }
#pragma unroll
      for (int d = 0; d < 4; ++d)
#pragma unroll
        for (int r = 0; r < 4; ++r) o[d][r] *= fac[r];
#pragma unroll
      for (int r = 0; r < 4; ++r) ol[r] *= fac[r];
      // O += P V ; l += P @ ones
      __builtin_amdgcn_s_setprio(1);
#pragma unroll
      for (int ks = 0; ks < 2; ++ks) {
        const bf16x8 pf = *(const bf16x8*)&Ps[w][c][ks ? pro1 : pro0];
#pragma unroll
        for (int d = 0; d < 4; ++d) {
          const bf16x8 vf = *(const bf16x8*)&Vs[cur][(d * 16 + c) * 64 + (ks ? pro1 : pro0)];
          o[d] = mfma16(pf, vf, o[d]);
        }
        ol = mfma16(pf, onef, ol);
      }
      __builtin_amdgcn_s_setprio(0);
      cur = nx1;
      nx1 = (nx1 + 1 == 3) ? 0 : nx1 + 1;
    }
#pragma unroll
    for (int d = 0; d < 4; ++d)
#pragma unroll
      for (int r = 0; r < 4; ++r) {
        const float v = o[d][r] / ol[r];
        ctx[(size_t)(b * 2048 + q0 + w * 16 + g * 4 + r) * 1024 + h * 64 + d * 16 + c] = f2bf(v);
      }
  }
#undef ATTN_LOAD
#undef ATTN_WRITE
}

// ---------------- launch ----------------

extern "C" void kernel_launch(void* const* d_in, const int* in_sizes, int n_in,
                              void* d_out, int out_size, void* d_ws, size_t ws_size,
                              hipStream_t stream) {
  const float* hidden = (const float*)d_in[0];
  const float* ln1g = (const float*)d_in[1];
  const float* ln1b = (const float*)d_in[2];
  const float* ln2g = (const float*)d_in[3];
  const float* ln2b = (const float*)d_in[4];
  const float* qU = (const float*)d_in[5];
  const float* qV = (const float*)d_in[6];
  const float* qb = (const float*)d_in[7];
  const float* kU = (const float*)d_in[8];
  const float* kV = (const float*)d_in[9];
  const float* kb = (const float*)d_in[10];
  const float* vU = (const float*)d_in[11];
  const float* vV = (const float*)d_in[12];
  const float* vb = (const float*)d_in[13];
  const float* outU = (const float*)d_in[14];
  const float* outV = (const float*)d_in[15];
  const float* outb = (const float*)d_in[16];
  const float* fc1U = (const float*)d_in[17];
  const float* fc1V = (const float*)d_in[18];
  const float* fc1b = (const float*)d_in[19];
  const float* fc2U = (const float*)d_in[20];
  const float* fc2V = (const float*)d_in[21];
  const float* fc2b = (const float*)d_in[22];
  float* out = (float*)d_out;

  // workspace carve, lifetime-based aliasing
  char* p = (char*)d_ws;
  unsigned short* x1x2 = (unsigned short*)p; p += (size_t)4096 * 1024 * 2;   // x1 (LN1), later x2 (LN2)
  unsigned short* WqT_t1 = (unsigned short*)p; p += (size_t)3072 * 1024 * 2; // Wqkv^T, later t1
  float* bqkv = (float*)p; p += 3072 * 4;
  char* bigA = p; p += (size_t)4096 * 3072 * 2 + (size_t)4096 * 1024 * 2;    // QKV + ctx, later hmid
  unsigned short* QKV = (unsigned short*)bigA;
  unsigned short* ctxb = (unsigned short*)(bigA + (size_t)4096 * 3072 * 2);
  unsigned short* hmid = (unsigned short*)bigA;
  char* wo = p; p += (size_t)1024 * 768 * 2 * 2 + (size_t)1024 * 1024 * 2;   // outU,outV^T,Wout^T, later t2
  unsigned short* outUb = (unsigned short*)wo;
  unsigned short* outVT = (unsigned short*)(wo + (size_t)1024 * 768 * 2);
  unsigned short* WoutT = (unsigned short*)(wo + (size_t)1024 * 768 * 2 * 2);
  unsigned short* t2 = (unsigned short*)wo;
  float* hbuf = (float*)p; p += (size_t)4096 * 1024 * 4;                     // h (fp32 residual); VT aliases pre-attn
  unsigned short* VT = (unsigned short*)hbuf;                                // [32][64][2048] bf16 = 8MB
  unsigned short* fc1UT = (unsigned short*)p; p += (size_t)512 * 1024 * 2;
  unsigned short* fc1VT = (unsigned short*)p; p += (size_t)4096 * 512 * 2;
  unsigned short* fc2UT = (unsigned short*)p; p += (size_t)512 * 4096 * 2;
  unsigned short* fc2VT = (unsigned short*)p; p += (size_t)1024 * 512 * 2;

  const dim3 b256(256);
  const dim3 tb(32, 8);

  // weight prep
  concat_bias_k<<<12, b256, 0, stream>>>(qb, kb, vb, bqkv);
  wqkv_pre_k<<<dim3(16, 48), b256, 0, stream>>>(qU, qV, kU, kV, vU, vV, WqT_t1);
  tcvt_k<<<dim3(32, 24), tb, 0, stream>>>(outV, outVT, 768, 1024);
  cvt_k<<<768, b256, 0, stream>>>(outU, outUb, 1024 * 768);
  tcvt_k<<<dim3(16, 32), tb, 0, stream>>>(fc1U, fc1UT, 1024, 512);
  tcvt_k<<<dim3(128, 16), tb, 0, stream>>>(fc1V, fc1VT, 512, 4096);
  tcvt_k<<<dim3(16, 128), tb, 0, stream>>>(fc2U, fc2UT, 4096, 512);
  tcvt_k<<<dim3(32, 16), tb, 0, stream>>>(fc2V, fc2VT, 512, 1024);

  // attention path
  ln_k<<<4096, b256, 0, stream>>>(hidden, ln1g, ln1b, x1x2);
  gemm_k<128, 128, 1, 1><<<dim3(24, 32), b256, 0, stream>>>(x1x2, WqT_t1, bqkv, nullptr, QKV, 4096, 3072, 1024);
  vtr_k<<<dim3(64, 2, 32), tb, 0, stream>>>(QKV, VT);
  gemm_k<128, 128, 0, 1><<<dim3(8, 8), b256, 0, stream>>>(outVT, outUb, nullptr, nullptr, WoutT, 1024, 1024, 768);
  attn_k<<<dim3(16, 32), b256, 0, stream>>>(QKV, VT, ctxb);
  gemm_k<64, 128, 3, 0><<<dim3(8, 64), b256, 0, stream>>>(ctxb, WoutT, outb, hidden, hbuf, 4096, 1024, 1024);

  // MLP path
  ln_k<<<4096, b256, 0, stream>>>(hbuf, ln2g, ln2b, x1x2);
  gemm_k<64, 64, 0, 1><<<dim3(8, 64), b256, 0, stream>>>(x1x2, fc1UT, nullptr, nullptr, WqT_t1, 4096, 512, 1024);
  gemm_k<128, 128, 2, 1><<<dim3(32, 32), b256, 0, stream>>>(WqT_t1, fc1VT, fc1b, nullptr, hmid, 4096, 4096, 512);
  gemm_k<64, 64, 0, 1><<<dim3(8, 64), b256, 0, stream>>>(hmid, fc2UT, nullptr, nullptr, t2, 4096, 512, 4096);
  gemm_k<64, 128, 3, 0><<<dim3(8, 64), b256, 0, stream>>>(t2, fc2VT, fc2b, hbuf, out, 4096, 1024, 512);
}

// Round 7
// 313.703 us; speedup vs baseline: 1.5552x; 1.0183x over previous
//
#include <hip/hip_runtime.h>
#include <hip/hip_bf16.h>

typedef float f32x4 __attribute__((ext_vector_type(4)));
typedef __bf16 bf16x8 __attribute__((ext_vector_type(8)));
typedef unsigned short u16x8 __attribute__((ext_vector_type(8)));
typedef unsigned short u16x4 __attribute__((ext_vector_type(4)));

#define QSCALE 0.180336881f  /* 0.125 * log2(e): folds attn scale + exp2 domain into Q */

__device__ __forceinline__ unsigned short f2bf(float f) {
  union { float f; unsigned int u; } v; v.f = f;
  return (unsigned short)((v.u + 0x7FFFu + ((v.u >> 16) & 1u)) >> 16);
}

__device__ __forceinline__ f32x4 mfma16(bf16x8 a, bf16x8 b, f32x4 c) {
  return __builtin_amdgcn_mfma_f32_16x16x32_bf16(a, b, c, 0, 0, 0);
}

__device__ __forceinline__ void gload16(const unsigned short* g, unsigned short* l) {
  __builtin_amdgcn_global_load_lds(
      (const __attribute__((address_space(1))) void*)g,
      (__attribute__((address_space(3))) void*)l, 16, 0, 0);
}

// ---------------- small utility kernels ----------------

__global__ void concat_bias_k(const float* __restrict__ qb, const float* __restrict__ kb,
                              const float* __restrict__ vb, float* __restrict__ out) {
  const int i = blockIdx.x * 256 + threadIdx.x;
  if (i >= 3072) return;
  const float* s = (i < 1024) ? qb : (i < 2048 ? kb : vb);
  out[i] = s[i & 1023] * (i < 1024 ? QSCALE : 1.0f);
}

// fp32 [R,C] -> bf16 [C,R]
__global__ void tcvt_k(const float* __restrict__ in, unsigned short* __restrict__ out,
                       int R, int C) {
  __shared__ float tile[32][33];
  const int x = blockIdx.x * 32 + threadIdx.x;
  const int y0 = blockIdx.y * 32;
#pragma unroll
  for (int i = 0; i < 32; i += 8)
    tile[threadIdx.y + i][threadIdx.x] = in[(size_t)(y0 + threadIdx.y + i) * C + x];
  __syncthreads();
  const int ox = y0 + threadIdx.x;
  const int oy0 = blockIdx.x * 32;
#pragma unroll
  for (int i = 0; i < 32; i += 8)
    out[(size_t)(oy0 + threadIdx.y + i) * R + ox] = f2bf(tile[threadIdx.x][threadIdx.y + i]);
}

__global__ void cvt_k(const float* __restrict__ in, unsigned short* __restrict__ out, int n) {
  const int i = (blockIdx.x * 256 + threadIdx.x) * 4;
  if (i >= n) return;
  const f32x4 v = *(const f32x4*)(in + i);
  u16x4 o;
#pragma unroll
  for (int k = 0; k < 4; ++k) o[k] = f2bf(v[k]);
  *(u16x4*)(out + i) = o;
}

// V-transpose: QKV[b][s][2048 + h*64 + d] -> VT[(b*16+h)][d][s]  (bf16)
__global__ void vtr_k(const unsigned short* __restrict__ QKV, unsigned short* __restrict__ VT) {
  __shared__ unsigned short tile[32][33];
  const int bh = blockIdx.z, b = bh >> 4, h = bh & 15;
  const int s0 = blockIdx.x * 32, d0 = blockIdx.y * 32;
  const unsigned short* src = QKV + (size_t)b * 2048 * 3072 + 2048 + h * 64;
#pragma unroll
  for (int i = 0; i < 32; i += 8)
    tile[threadIdx.y + i][threadIdx.x] = src[(size_t)(s0 + threadIdx.y + i) * 3072 + d0 + threadIdx.x];
  __syncthreads();
  unsigned short* dst = VT + (size_t)bh * 64 * 2048;
#pragma unroll
  for (int i = 0; i < 32; i += 8)
    dst[(size_t)(d0 + threadIdx.y + i) * 2048 + s0 + threadIdx.x] = tile[threadIdx.x][threadIdx.y + i];
}

// Wqkv^T[(m*1024 + h*64 + e)*1024 + d] = sum_r U_m[d,h,r] * V_m[h,r,e]  (Q part scaled)
__global__ __launch_bounds__(256) void wqkv_pre_k(
    const float* __restrict__ qU, const float* __restrict__ qV,
    const float* __restrict__ kU, const float* __restrict__ kV,
    const float* __restrict__ vU, const float* __restrict__ vV,
    unsigned short* __restrict__ WT) {
  __shared__ float Us[64][48];
  __shared__ float Vs[48][64];
  const int m = blockIdx.y >> 4, h = blockIdx.y & 15;
  const int d0 = blockIdx.x * 64;
  const float* U = (m == 0) ? qU : (m == 1 ? kU : vU);
  const float* V = (m == 0) ? qV : (m == 1 ? kV : vV);
  const float qs = (m == 0) ? QSCALE : 1.0f;
  const int t = threadIdx.x;
  for (int idx = t; idx < 64 * 48; idx += 256) {
    const int d = idx / 48, r = idx - d * 48;
    Us[d][r] = U[(size_t)(d0 + d) * 768 + h * 48 + r];
  }
  for (int idx = t; idx < 48 * 64; idx += 256) {
    const int r = idx >> 6, e = idx & 63;
    Vs[r][e] = V[(h * 48 + r) * 64 + e];
  }
  __syncthreads();
  const int e = t & 63, dg = t >> 6;
  for (int j = 0; j < 16; ++j) {
    const int d = dg * 16 + j;
    float s = 0.f;
#pragma unroll
    for (int r = 0; r < 48; ++r) s = fmaf(Us[d][r], Vs[r][e], s);
    WT[(size_t)(m * 1024 + h * 64 + e) * 1024 + d0 + d] = f2bf(s * qs);
  }
}

// LayerNorm over D=1024, fp32 in, bf16 out. One block per row.
__global__ __launch_bounds__(256) void ln_k(
    const float* __restrict__ in, const float* __restrict__ gw,
    const float* __restrict__ bw, unsigned short* __restrict__ out) {
  const int row = blockIdx.x, t = threadIdx.x;
  const f32x4 v = *(const f32x4*)(in + (size_t)row * 1024 + t * 4);
  float s = v[0] + v[1] + v[2] + v[3];
  float ss = v[0] * v[0] + v[1] * v[1] + v[2] * v[2] + v[3] * v[3];
#pragma unroll
  for (int off = 1; off < 64; off <<= 1) {
    s += __shfl_xor(s, off);
    ss += __shfl_xor(ss, off);
  }
  __shared__ float red[8];
  if ((t & 63) == 0) { red[(t >> 6) * 2] = s; red[(t >> 6) * 2 + 1] = ss; }
  __syncthreads();
  s = red[0] + red[2] + red[4] + red[6];
  ss = red[1] + red[3] + red[5] + red[7];
  const float mean = s * (1.0f / 1024.0f);
  const float rstd = rsqrtf(ss * (1.0f / 1024.0f) - mean * mean + 1e-5f);
  const f32x4 g4 = *(const f32x4*)(gw + t * 4);
  const f32x4 b4 = *(const f32x4*)(bw + t * 4);
  u16x4 o;
#pragma unroll
  for (int i = 0; i < 4; ++i) o[i] = f2bf((v[i] - mean) * rstd * g4[i] + b4[i]);
  *(u16x4*)(out + (size_t)row * 1024 + t * 4) = o;
}

// bijective XCD chunking (m157/m204): XCD c gets a contiguous chunk of the
// bx-fastest block order -> same-A-panel (or same-head) blocks share one L2.
__device__ __forceinline__ void xcd_swz(int& bx, int& by, int nx, int ny) {
  const int nwg = nx * ny;
  if ((nwg & 7) == 0) {
    const int d = by * nx + bx;
    const int k = (d & 7) * (nwg >> 3) + (d >> 3);
    bx = k % nx;
    by = k / nx;
  }
}

// ---------------- generic bf16 MFMA GEMM (double-buffered global_load_lds) ----------------
// C[M,N] = A[M,K] @ Bt[N,K]^T. BM in {64,128}, BN in {64,128}. 256 threads = 4 waves
// (2x2), wave tile (BM/2)x(BN/2), 16x16x32 MFMA. One barrier per K-step (BK=32).
template <int BM, int BN, int EPI, int OUTBF>
__global__ __launch_bounds__(256) void gemm_k(
    const unsigned short* __restrict__ A, const unsigned short* __restrict__ Bt,
    const float* __restrict__ bias, const float* __restrict__ resid,
    void* __restrict__ Cout, int M, int N, int K) {
  constexpr int MI = BM / 32;
  constexpr int FN = BN / 32;
  __shared__ unsigned short As[2][BM * 32];
  __shared__ unsigned short Bs[2][BN * 32];
  int bxi = blockIdx.x, byi = blockIdx.y;
  xcd_swz(bxi, byi, gridDim.x, gridDim.y);
  const int t = threadIdx.x;
  const int lane = t & 63, wid = t >> 6;
  const int m0 = byi * BM, n0 = bxi * BN;
  const int wm = (wid >> 1) * (BM / 2), wn = (wid & 1) * (BN / 2);
  const int fr = lane & 15, fg = (lane >> 4) * 8;

  f32x4 acc[MI][FN];
#pragma unroll
  for (int i = 0; i < MI; ++i)
#pragma unroll
    for (int j = 0; j < FN; ++j) acc[i][j] = (f32x4){0.f, 0.f, 0.f, 0.f};

  const unsigned short* Ag0 = A + (size_t)(m0 + (t >> 2)) * K + (t & 3) * 8;
  const unsigned short* Ag1 = A + (size_t)(m0 + 64 + (t >> 2)) * K + (t & 3) * 8;
  const unsigned short* Bg0 = Bt + (size_t)(n0 + (t >> 2)) * K + (t & 3) * 8;
  const unsigned short* Bg1 = Bt + (size_t)(n0 + 64 + (t >> 2)) * K + (t & 3) * 8;
  const int l0 = t * 8;

#define GEMM_STAGE(buf, ke)                                   \
  {                                                           \
    gload16(Ag0 + (ke), &As[buf][l0]);                        \
    if (BM == 128) gload16(Ag1 + (ke), &As[buf][l0 + 2048]);  \
    gload16(Bg0 + (ke), &Bs[buf][l0]);                        \
    if (BN == 128) gload16(Bg1 + (ke), &Bs[buf][l0 + 2048]);  \
  }

  const int nk = K >> 5;
  GEMM_STAGE(0, 0);

  for (int kt = 0; kt < nk; ++kt) {
    const int cur = kt & 1;
    __syncthreads();
    if (kt + 1 < nk) GEMM_STAGE(cur ^ 1, (kt + 1) * 32);
    bf16x8 af[MI], bfr[FN];
#pragma unroll
    for (int i = 0; i < MI; ++i) af[i] = *(const bf16x8*)&As[cur][(wm + i * 16 + fr) * 32 + fg];
#pragma unroll
    for (int j = 0; j < FN; ++j) bfr[j] = *(const bf16x8*)&Bs[cur][(wn + j * 16 + fr) * 32 + fg];
#pragma unroll
    for (int i = 0; i < MI; ++i)
#pragma unroll
      for (int j = 0; j < FN; ++j) acc[i][j] = mfma16(af[i], bfr[j], acc[i][j]);
  }
#undef GEMM_STAGE

#pragma unroll
  for (int j = 0; j < FN; ++j) {
    const int col = n0 + wn + j * 16 + fr;
    const float bval = (EPI >= 1) ? bias[col] : 0.0f;
#pragma unroll
    for (int i = 0; i < MI; ++i) {
#pragma unroll
      for (int r = 0; r < 4; ++r) {
        const int row = m0 + wm + i * 16 + ((lane >> 4) << 2) + r;
        float v = acc[i][j][r] + bval;
        if (EPI == 2) {  // gelu tanh-approx: v * sigmoid(2z)
          const float z = 0.7978845608028654f * (v + 0.044715f * v * v * v);
          v = v - v / (__expf(2.0f * z) + 1.0f);
        }
        if (EPI == 3) v += resid[(size_t)row * N + col];
        if (OUTBF)
          ((unsigned short*)Cout)[(size_t)row * N + col] = f2bf(v);
        else
          ((float*)Cout)[(size_t)row * N + col] = v;
      }
    }
  }
}

// ---------------- causal flash attention ----------------
// Reg-staged K/V -> swizzled LDS, 2 buffers, 2 barriers/iter; prefetch regs
// loaded one full compute-phase before their ds_write consumes them (T14).
// LDS 40KB -> 4 blocks/CU; grid (32,32) qt=31-bx (LPT), XCD-chunked so
// same-head blocks share one L2. Q pre-scaled by 0.125*log2e (exp2 domain);
// row-sum via ones-fragment MFMA.
__global__ __launch_bounds__(256) void attn_k(
    const unsigned short* __restrict__ QKV, const unsigned short* __restrict__ VT,
    unsigned short* __restrict__ ctx) {
  __shared__ unsigned short Ks[2][64 * 64];
  __shared__ unsigned short Vs[2][64 * 64];
  __shared__ __bf16 Ps[4][16][64];  // chunk-swizzled: source chunk s stored at s^(row&7)
  int bxi = blockIdx.x, byi = blockIdx.y;
  xcd_swz(bxi, byi, 32, 32);
  const int qt = 31 - bxi, bh = byi;
  const int nt = qt + 1;
  const int b = bh >> 4, h = bh & 15;
  const int t = threadIdx.x, lane = t & 63, w = t >> 6;
  const int g = lane >> 4, c = lane & 15;
  const int cks = c & 7;
  const int q0 = qt * 64;
  const size_t base = (size_t)b * 2048 * 3072;

  // staging geometry: thread t covers tile row r0 = t>>2, source chunks ch0, ch0+1
  const int r0 = t >> 2;
  const int ch0 = (t & 3) * 2;
  const int lw0 = r0 * 64 + ((ch0 ^ (r0 & 7)) * 8);
  const int lw1 = r0 * 64 + (((ch0 + 1) ^ (r0 & 7)) * 8);
  const unsigned short* Kg = QKV + base + 1024 + h * 64 + (size_t)r0 * 3072 + ch0 * 8;
  const unsigned short* Vg = VT + ((size_t)bh * 64 + r0) * 2048 + ch0 * 8;

  // loop-invariant swizzled read offsets
  const int kro0 = (g ^ cks) * 8, kro1 = ((4 + g) ^ cks) * 8;

  bf16x8 onef;
#pragma unroll
  for (int i = 0; i < 8; ++i) onef[i] = (__bf16)1.0f;

  const unsigned short* qp = QKV + base + (size_t)(q0 + w * 16 + c) * 3072 + h * 64 + g * 8;
  const bf16x8 qf0 = *(const bf16x8*)qp;
  const bf16x8 qf1 = *(const bf16x8*)(qp + 32);

  f32x4 o[4];
#pragma unroll
  for (int d = 0; d < 4; ++d) o[d] = (f32x4){0.f, 0.f, 0.f, 0.f};
  f32x4 ol = (f32x4){0.f, 0.f, 0.f, 0.f};
  float mrow[4];
#pragma unroll
  for (int r = 0; r < 4; ++r) mrow[r] = -1e30f;

  u16x8 kr0, kr1, vr0, vr1;

#define ATTN_LOAD(kt_)                                      \
  {                                                         \
    const size_t ko = (size_t)(kt_) * 64 * 3072;            \
    const int vo = (kt_) * 64;                              \
    kr0 = *(const u16x8*)(Kg + ko);                         \
    kr1 = *(const u16x8*)(Kg + ko + 8);                     \
    vr0 = *(const u16x8*)(Vg + vo);                         \
    vr1 = *(const u16x8*)(Vg + vo + 8);                     \
  }
#define ATTN_WRITE(buf)                                     \
  {                                                         \
    *(u16x8*)&Ks[buf][lw0] = kr0;                           \
    *(u16x8*)&Ks[buf][lw1] = kr1;                           \
    *(u16x8*)&Vs[buf][lw0] = vr0;                           \
    *(u16x8*)&Vs[buf][lw1] = vr1;                           \
  }

  ATTN_LOAD(0);
  ATTN_WRITE(0);
  if (nt > 1) ATTN_LOAD(1);
  __syncthreads();

  for (int j = 0; j < nt; ++j) {
    const int cur = j & 1;

    // S = Q K^T (exp2 domain). C layout: col=key=c, row=q=4g+r
    f32x4 s4[4];
    __builtin_amdgcn_s_setprio(1);
#pragma unroll
    for (int t16 = 0; t16 < 4; ++t16) {
      const int krow = (t16 * 16 + c) * 64;
      const bf16x8 kf0 = *(const bf16x8*)&Ks[cur][krow + kro0];
      const bf16x8 kf1 = *(const bf16x8*)&Ks[cur][krow + kro1];
      f32x4 a = (f32x4){0.f, 0.f, 0.f, 0.f};
      a = mfma16(qf0, kf0, a);
      a = mfma16(qf1, kf1, a);
      s4[t16] = a;
    }
    __builtin_amdgcn_s_setprio(0);
    if (j == qt) {  // diagonal tile: causal mask
      const int qbase = q0 + w * 16 + g * 4;
      const int kbase = j * 64 + c;
#pragma unroll
      for (int t16 = 0; t16 < 4; ++t16)
#pragma unroll
        for (int r = 0; r < 4; ++r)
          if (kbase + t16 * 16 > qbase + r) s4[t16][r] = -1e30f;
    }
    // online softmax: max over 16 key-lanes
    float mx[4];
#pragma unroll
    for (int r = 0; r < 4; ++r)
      mx[r] = fmaxf(fmaxf(s4[0][r], s4[1][r]), fmaxf(s4[2][r], s4[3][r]));
#pragma unroll
    for (int off = 1; off < 16; off <<= 1)
#pragma unroll
      for (int r = 0; r < 4; ++r) mx[r] = fmaxf(mx[r], __shfl_xor(mx[r], off));
    float fac[4];
#pragma unroll
    for (int r = 0; r < 4; ++r) {
      const float mn = fmaxf(mrow[r], mx[r]);
      fac[r] = exp2f(mrow[r] - mn);
      mrow[r] = mn;
    }
#pragma unroll
    for (int t16 = 0; t16 < 4; ++t16)
#pragma unroll
      for (int r = 0; r < 4; ++r) {
        const int q = g * 4 + r;
        const int col = (((t16 * 2 + (c >> 3)) ^ (q & 7)) * 8) + cks;
        Ps[w][q][col] = (__bf16)exp2f(s4[t16][r] - mrow[r]);
      }
#pragma unroll
    for (int d = 0; d < 4; ++d)
#pragma unroll
      for (int r = 0; r < 4; ++r) o[d][r] *= fac[r];
#pragma unroll
    for (int r = 0; r < 4; ++r) ol[r] *= fac[r];
    // O += P V ; l += P @ ones
    __builtin_amdgcn_s_setprio(1);
#pragma unroll
    for (int ks = 0; ks < 2; ++ks) {
      const bf16x8 pf = *(const bf16x8*)&Ps[w][c][ks ? kro1 : kro0];
#pragma unroll
      for (int d = 0; d < 4; ++d) {
        const bf16x8 vf = *(const bf16x8*)&Vs[cur][(d * 16 + c) * 64 + (ks ? kro1 : kro0)];
        o[d] = mfma16(pf, vf, o[d]);
      }
      ol = mfma16(pf, onef, ol);
    }
    __builtin_amdgcn_s_setprio(0);

    if (j + 1 < nt) {
      __syncthreads();       // iter j-1's reads of buf[cur^1] done everywhere
      ATTN_WRITE(cur ^ 1);   // tile j+1 (vmcnt wait lands here, ~1 iter after issue)
      if (j + 2 < nt) ATTN_LOAD(j + 2);
      __syncthreads();       // buf[cur^1] visible before iter j+1 reads it
    }
  }
#pragma unroll
  for (int d = 0; d < 4; ++d)
#pragma unroll
    for (int r = 0; r < 4; ++r) {
      const float v = o[d][r] / ol[r];
      ctx[(size_t)(b * 2048 + q0 + w * 16 + g * 4 + r) * 1024 + h * 64 + d * 16 + c] = f2bf(v);
    }
#undef ATTN_LOAD
#undef ATTN_WRITE
}

// ---------------- launch ----------------

extern "C" void kernel_launch(void* const* d_in, const int* in_sizes, int n_in,
                              void* d_out, int out_size, void* d_ws, size_t ws_size,
                              hipStream_t stream) {
  const float* hidden = (const float*)d_in[0];
  const float* ln1g = (const float*)d_in[1];
  const float* ln1b = (const float*)d_in[2];
  const float* ln2g = (const float*)d_in[3];
  const float* ln2b = (const float*)d_in[4];
  const float* qU = (const float*)d_in[5];
  const float* qV = (const float*)d_in[6];
  const float* qb = (const float*)d_in[7];
  const float* kU = (const float*)d_in[8];
  const float* kV = (const float*)d_in[9];
  const float* kb = (const float*)d_in[10];
  const float* vU = (const float*)d_in[11];
  const float* vV = (const float*)d_in[12];
  const float* vb = (const float*)d_in[13];
  const float* outU = (const float*)d_in[14];
  const float* outV = (const float*)d_in[15];
  const float* outb = (const float*)d_in[16];
  const float* fc1U = (const float*)d_in[17];
  const float* fc1V = (const float*)d_in[18];
  const float* fc1b = (const float*)d_in[19];
  const float* fc2U = (const float*)d_in[20];
  const float* fc2V = (const float*)d_in[21];
  const float* fc2b = (const float*)d_in[22];
  float* out = (float*)d_out;

  // workspace carve, lifetime-based aliasing
  char* p = (char*)d_ws;
  unsigned short* x1x2 = (unsigned short*)p; p += (size_t)4096 * 1024 * 2;   // x1 (LN1), later x2 (LN2)
  unsigned short* WqT_t1 = (unsigned short*)p; p += (size_t)3072 * 1024 * 2; // Wqkv^T, later t1
  float* bqkv = (float*)p; p += 3072 * 4;
  char* bigA = p; p += (size_t)4096 * 3072 * 2 + (size_t)4096 * 1024 * 2;    // QKV + ctx, later hmid
  unsigned short* QKV = (unsigned short*)bigA;
  unsigned short* ctxb = (unsigned short*)(bigA + (size_t)4096 * 3072 * 2);
  unsigned short* hmid = (unsigned short*)bigA;
  char* wo = p; p += (size_t)1024 * 768 * 2 * 2 + (size_t)1024 * 1024 * 2;   // outU,outV^T,Wout^T, later t2
  unsigned short* outUb = (unsigned short*)wo;
  unsigned short* outVT = (unsigned short*)(wo + (size_t)1024 * 768 * 2);
  unsigned short* WoutT = (unsigned short*)(wo + (size_t)1024 * 768 * 2 * 2);
  unsigned short* t2 = (unsigned short*)wo;
  float* hbuf = (float*)p; p += (size_t)4096 * 1024 * 4;                     // h (fp32 residual); VT aliases pre-attn
  unsigned short* VT = (unsigned short*)hbuf;                                // [32][64][2048] bf16 = 8MB
  unsigned short* fc1UT = (unsigned short*)p; p += (size_t)512 * 1024 * 2;
  unsigned short* fc1VT = (unsigned short*)p; p += (size_t)4096 * 512 * 2;
  unsigned short* fc2UT = (unsigned short*)p; p += (size_t)512 * 4096 * 2;
  unsigned short* fc2VT = (unsigned short*)p; p += (size_t)1024 * 512 * 2;

  const dim3 b256(256);
  const dim3 tb(32, 8);

  // weight prep
  concat_bias_k<<<12, b256, 0, stream>>>(qb, kb, vb, bqkv);
  wqkv_pre_k<<<dim3(16, 48), b256, 0, stream>>>(qU, qV, kU, kV, vU, vV, WqT_t1);
  tcvt_k<<<dim3(32, 24), tb, 0, stream>>>(outV, outVT, 768, 1024);
  cvt_k<<<768, b256, 0, stream>>>(outU, outUb, 1024 * 768);
  tcvt_k<<<dim3(16, 32), tb, 0, stream>>>(fc1U, fc1UT, 1024, 512);
  tcvt_k<<<dim3(128, 16), tb, 0, stream>>>(fc1V, fc1VT, 512, 4096);
  tcvt_k<<<dim3(16, 128), tb, 0, stream>>>(fc2U, fc2UT, 4096, 512);
  tcvt_k<<<dim3(32, 16), tb, 0, stream>>>(fc2V, fc2VT, 512, 1024);

  // attention path
  ln_k<<<4096, b256, 0, stream>>>(hidden, ln1g, ln1b, x1x2);
  gemm_k<128, 128, 1, 1><<<dim3(24, 32), b256, 0, stream>>>(x1x2, WqT_t1, bqkv, nullptr, QKV, 4096, 3072, 1024);
  vtr_k<<<dim3(64, 2, 32), tb, 0, stream>>>(QKV, VT);
  gemm_k<128, 128, 0, 1><<<dim3(8, 8), b256, 0, stream>>>(outVT, outUb, nullptr, nullptr, WoutT, 1024, 1024, 768);
  attn_k<<<dim3(32, 32), b256, 0, stream>>>(QKV, VT, ctxb);
  gemm_k<64, 128, 3, 0><<<dim3(8, 64), b256, 0, stream>>>(ctxb, WoutT, outb, hidden, hbuf, 4096, 1024, 1024);

  // MLP path
  ln_k<<<4096, b256, 0, stream>>>(hbuf, ln2g, ln2b, x1x2);
  gemm_k<64, 64, 0, 1><<<dim3(8, 64), b256, 0, stream>>>(x1x2, fc1UT, nullptr, nullptr, WqT_t1, 4096, 512, 1024);
  gemm_k<128, 128, 2, 1><<<dim3(32, 32), b256, 0, stream>>>(WqT_t1, fc1VT, fc1b, nullptr, hmid, 4096, 4096, 512);
  gemm_k<64, 64, 0, 1><<<dim3(8, 64), b256, 0, stream>>>(hmid, fc2UT, nullptr, nullptr, t2, 4096, 512, 4096);
  gemm_k<64, 128, 3, 0><<<dim3(8, 64), b256, 0, stream>>>(t2, fc2VT, fc2b, hbuf, out, 4096, 1024, 512);
}

// Round 8
// 291.412 us; speedup vs baseline: 1.6742x; 1.0765x over previous
//
#include <hip/hip_runtime.h>
#include <hip/hip_bf16.h>

typedef float f32x4 __attribute__((ext_vector_type(4)));
typedef __bf16 bf16x8 __attribute__((ext_vector_type(8)));
typedef __bf16 bf16x4 __attribute__((ext_vector_type(4)));
typedef unsigned short u16x8 __attribute__((ext_vector_type(8)));
typedef unsigned short u16x4 __attribute__((ext_vector_type(4)));

#define QSCALE 0.180336881f  /* 0.125 * log2(e): folds attn scale + exp2 domain into Q */

__device__ __forceinline__ unsigned short f2bf(float f) {
  union { float f; unsigned int u; } v; v.f = f;
  return (unsigned short)((v.u + 0x7FFFu + ((v.u >> 16) & 1u)) >> 16);
}

__device__ __forceinline__ f32x4 mfma16(bf16x8 a, bf16x8 b, f32x4 c) {
  return __builtin_amdgcn_mfma_f32_16x16x32_bf16(a, b, c, 0, 0, 0);
}

__device__ __forceinline__ void gload16(const unsigned short* g, unsigned short* l) {
  __builtin_amdgcn_global_load_lds(
      (const __attribute__((address_space(1))) void*)g,
      (__attribute__((address_space(3))) void*)l, 16, 0, 0);
}

// ---------------- small utility kernels ----------------

__global__ void concat_bias_k(const float* __restrict__ qb, const float* __restrict__ kb,
                              const float* __restrict__ vb, float* __restrict__ out) {
  const int i = blockIdx.x * 256 + threadIdx.x;
  if (i >= 3072) return;
  const float* s = (i < 1024) ? qb : (i < 2048 ? kb : vb);
  out[i] = s[i & 1023] * (i < 1024 ? QSCALE : 1.0f);
}

// fp32 [R,C] -> bf16 [C,R]
__global__ void tcvt_k(const float* __restrict__ in, unsigned short* __restrict__ out,
                       int R, int C) {
  __shared__ float tile[32][33];
  const int x = blockIdx.x * 32 + threadIdx.x;
  const int y0 = blockIdx.y * 32;
#pragma unroll
  for (int i = 0; i < 32; i += 8)
    tile[threadIdx.y + i][threadIdx.x] = in[(size_t)(y0 + threadIdx.y + i) * C + x];
  __syncthreads();
  const int ox = y0 + threadIdx.x;
  const int oy0 = blockIdx.x * 32;
#pragma unroll
  for (int i = 0; i < 32; i += 8)
    out[(size_t)(oy0 + threadIdx.y + i) * R + ox] = f2bf(tile[threadIdx.x][threadIdx.y + i]);
}

__global__ void cvt_k(const float* __restrict__ in, unsigned short* __restrict__ out, int n) {
  const int i = (blockIdx.x * 256 + threadIdx.x) * 4;
  if (i >= n) return;
  const f32x4 v = *(const f32x4*)(in + i);
  u16x4 o;
#pragma unroll
  for (int k = 0; k < 4; ++k) o[k] = f2bf(v[k]);
  *(u16x4*)(out + i) = o;
}

// V-transpose: QKV[b][s][2048 + h*64 + d] -> VT[(b*16+h)][d][s]  (bf16)
__global__ void vtr_k(const unsigned short* __restrict__ QKV, unsigned short* __restrict__ VT) {
  __shared__ unsigned short tile[32][33];
  const int bh = blockIdx.z, b = bh >> 4, h = bh & 15;
  const int s0 = blockIdx.x * 32, d0 = blockIdx.y * 32;
  const unsigned short* src = QKV + (size_t)b * 2048 * 3072 + 2048 + h * 64;
#pragma unroll
  for (int i = 0; i < 32; i += 8)
    tile[threadIdx.y + i][threadIdx.x] = src[(size_t)(s0 + threadIdx.y + i) * 3072 + d0 + threadIdx.x];
  __syncthreads();
  unsigned short* dst = VT + (size_t)bh * 64 * 2048;
#pragma unroll
  for (int i = 0; i < 32; i += 8)
    dst[(size_t)(d0 + threadIdx.y + i) * 2048 + s0 + threadIdx.x] = tile[threadIdx.x][threadIdx.y + i];
}

// Wqkv^T[(m*1024 + h*64 + e)*1024 + d] = sum_r U_m[d,h,r] * V_m[h,r,e]  (Q part scaled)
__global__ __launch_bounds__(256) void wqkv_pre_k(
    const float* __restrict__ qU, const float* __restrict__ qV,
    const float* __restrict__ kU, const float* __restrict__ kV,
    const float* __restrict__ vU, const float* __restrict__ vV,
    unsigned short* __restrict__ WT) {
  __shared__ float Us[64][48];
  __shared__ float Vs[48][64];
  const int m = blockIdx.y >> 4, h = blockIdx.y & 15;
  const int d0 = blockIdx.x * 64;
  const float* U = (m == 0) ? qU : (m == 1 ? kU : vU);
  const float* V = (m == 0) ? qV : (m == 1 ? kV : vV);
  const float qs = (m == 0) ? QSCALE : 1.0f;
  const int t = threadIdx.x;
  for (int idx = t; idx < 64 * 48; idx += 256) {
    const int d = idx / 48, r = idx - d * 48;
    Us[d][r] = U[(size_t)(d0 + d) * 768 + h * 48 + r];
  }
  for (int idx = t; idx < 48 * 64; idx += 256) {
    const int r = idx >> 6, e = idx & 63;
    Vs[r][e] = V[(h * 48 + r) * 64 + e];
  }
  __syncthreads();
  const int e = t & 63, dg = t >> 6;
  for (int j = 0; j < 16; ++j) {
    const int d = dg * 16 + j;
    float s = 0.f;
#pragma unroll
    for (int r = 0; r < 48; ++r) s = fmaf(Us[d][r], Vs[r][e], s);
    WT[(size_t)(m * 1024 + h * 64 + e) * 1024 + d0 + d] = f2bf(s * qs);
  }
}

// LayerNorm over D=1024, fp32 in, bf16 out. One block per row.
__global__ __launch_bounds__(256) void ln_k(
    const float* __restrict__ in, const float* __restrict__ gw,
    const float* __restrict__ bw, unsigned short* __restrict__ out) {
  const int row = blockIdx.x, t = threadIdx.x;
  const f32x4 v = *(const f32x4*)(in + (size_t)row * 1024 + t * 4);
  float s = v[0] + v[1] + v[2] + v[3];
  float ss = v[0] * v[0] + v[1] * v[1] + v[2] * v[2] + v[3] * v[3];
#pragma unroll
  for (int off = 1; off < 64; off <<= 1) {
    s += __shfl_xor(s, off);
    ss += __shfl_xor(ss, off);
  }
  __shared__ float red[8];
  if ((t & 63) == 0) { red[(t >> 6) * 2] = s; red[(t >> 6) * 2 + 1] = ss; }
  __syncthreads();
  s = red[0] + red[2] + red[4] + red[6];
  ss = red[1] + red[3] + red[5] + red[7];
  const float mean = s * (1.0f / 1024.0f);
  const float rstd = rsqrtf(ss * (1.0f / 1024.0f) - mean * mean + 1e-5f);
  const f32x4 g4 = *(const f32x4*)(gw + t * 4);
  const f32x4 b4 = *(const f32x4*)(bw + t * 4);
  u16x4 o;
#pragma unroll
  for (int i = 0; i < 4; ++i) o[i] = f2bf((v[i] - mean) * rstd * g4[i] + b4[i]);
  *(u16x4*)(out + (size_t)row * 1024 + t * 4) = o;
}

// bijective XCD chunking (m157/m204): XCD c gets a contiguous chunk of the
// bx-fastest block order -> same-A-panel (or same-head) blocks share one L2.
__device__ __forceinline__ void xcd_swz(int& bx, int& by, int nx, int ny) {
  const int nwg = nx * ny;
  if ((nwg & 7) == 0) {
    const int d = by * nx + bx;
    const int k = (d & 7) * (nwg >> 3) + (d >> 3);
    bx = k % nx;
    by = k / nx;
  }
}

// ---------------- generic bf16 MFMA GEMM (double-buffered global_load_lds) ----------------
// C[M,N] = A[M,K] @ Bt[N,K]^T. BM in {64,128}, BN in {64,128}. 256 threads = 4 waves
// (2x2), wave tile (BM/2)x(BN/2), 16x16x32 MFMA. One barrier per K-step (BK=32).
template <int BM, int BN, int EPI, int OUTBF>
__global__ __launch_bounds__(256) void gemm_k(
    const unsigned short* __restrict__ A, const unsigned short* __restrict__ Bt,
    const float* __restrict__ bias, const float* __restrict__ resid,
    void* __restrict__ Cout, int M, int N, int K) {
  constexpr int MI = BM / 32;
  constexpr int FN = BN / 32;
  __shared__ unsigned short As[2][BM * 32];
  __shared__ unsigned short Bs[2][BN * 32];
  int bxi = blockIdx.x, byi = blockIdx.y;
  xcd_swz(bxi, byi, gridDim.x, gridDim.y);
  const int t = threadIdx.x;
  const int lane = t & 63, wid = t >> 6;
  const int m0 = byi * BM, n0 = bxi * BN;
  const int wm = (wid >> 1) * (BM / 2), wn = (wid & 1) * (BN / 2);
  const int fr = lane & 15, fg = (lane >> 4) * 8;

  f32x4 acc[MI][FN];
#pragma unroll
  for (int i = 0; i < MI; ++i)
#pragma unroll
    for (int j = 0; j < FN; ++j) acc[i][j] = (f32x4){0.f, 0.f, 0.f, 0.f};

  const unsigned short* Ag0 = A + (size_t)(m0 + (t >> 2)) * K + (t & 3) * 8;
  const unsigned short* Ag1 = A + (size_t)(m0 + 64 + (t >> 2)) * K + (t & 3) * 8;
  const unsigned short* Bg0 = Bt + (size_t)(n0 + (t >> 2)) * K + (t & 3) * 8;
  const unsigned short* Bg1 = Bt + (size_t)(n0 + 64 + (t >> 2)) * K + (t & 3) * 8;
  const int l0 = t * 8;

#define GEMM_STAGE(buf, ke)                                   \
  {                                                           \
    gload16(Ag0 + (ke), &As[buf][l0]);                        \
    if (BM == 128) gload16(Ag1 + (ke), &As[buf][l0 + 2048]);  \
    gload16(Bg0 + (ke), &Bs[buf][l0]);                        \
    if (BN == 128) gload16(Bg1 + (ke), &Bs[buf][l0 + 2048]);  \
  }

  const int nk = K >> 5;
  GEMM_STAGE(0, 0);

  for (int kt = 0; kt < nk; ++kt) {
    const int cur = kt & 1;
    __syncthreads();
    if (kt + 1 < nk) GEMM_STAGE(cur ^ 1, (kt + 1) * 32);
    bf16x8 af[MI], bfr[FN];
#pragma unroll
    for (int i = 0; i < MI; ++i) af[i] = *(const bf16x8*)&As[cur][(wm + i * 16 + fr) * 32 + fg];
#pragma unroll
    for (int j = 0; j < FN; ++j) bfr[j] = *(const bf16x8*)&Bs[cur][(wn + j * 16 + fr) * 32 + fg];
#pragma unroll
    for (int i = 0; i < MI; ++i)
#pragma unroll
      for (int j = 0; j < FN; ++j) acc[i][j] = mfma16(af[i], bfr[j], acc[i][j]);
  }
#undef GEMM_STAGE

#pragma unroll
  for (int j = 0; j < FN; ++j) {
    const int col = n0 + wn + j * 16 + fr;
    const float bval = (EPI >= 1) ? bias[col] : 0.0f;
#pragma unroll
    for (int i = 0; i < MI; ++i) {
#pragma unroll
      for (int r = 0; r < 4; ++r) {
        const int row = m0 + wm + i * 16 + ((lane >> 4) << 2) + r;
        float v = acc[i][j][r] + bval;
        if (EPI == 2) {  // gelu tanh-approx: v * sigmoid(2z)
          const float z = 0.7978845608028654f * (v + 0.044715f * v * v * v);
          v = v - v / (__expf(2.0f * z) + 1.0f);
        }
        if (EPI == 3) v += resid[(size_t)row * N + col];
        if (OUTBF)
          ((unsigned short*)Cout)[(size_t)row * N + col] = f2bf(v);
        else
          ((float*)Cout)[(size_t)row * N + col] = v;
      }
    }
  }
}

// ---------------- causal flash attention ----------------
// 8 waves (512 thr), 128-row Q-tile per block, 64-key KV tiles, reg-staged K/V
// into swizzled LDS (2 buffers, 2 barriers/iter). Swapped-operand QK^T
// (mfma(K,Q): col=q, row=key) makes softmax state scalar per lane (q = lane&15):
// 15 in-reg fmax + 2 shfl for the max, Ps written as 4x b64 packed bf16,
// fac redistributed to o-rows via 4 shfl. Row-sum via ones-fragment MFMA.
// Grid (16,32); qi = ((byi>>1)&1) ? 15-bxi : bxi gives every CU a uniform
// 36-iter load under the XCD chunking. LDS 48KB -> 2 blocks/CU sustained.
__global__ __launch_bounds__(512) void attn_k(
    const unsigned short* __restrict__ QKV, const unsigned short* __restrict__ VT,
    unsigned short* __restrict__ ctx) {
  __shared__ unsigned short Ks[2][64 * 64];
  __shared__ unsigned short Vs[2][64 * 64];
  __shared__ unsigned short Ps[8][16 * 64];  // per-wave P, 16B-chunk swizzled by q&7
  int bxi = blockIdx.x, byi = blockIdx.y;
  xcd_swz(bxi, byi, 16, 32);
  const int qi = ((byi >> 1) & 1) ? (15 - bxi) : bxi;
  const int bh = byi, b = bh >> 4, h = bh & 15;
  const int nt = 2 * qi + 2;
  const int q0b = qi * 128;
  const int t = threadIdx.x, lane = t & 63, w = t >> 6;
  const int g = lane >> 4, c = lane & 15;
  const int cks = c & 7;
  const size_t base = (size_t)b * 2048 * 3072;

  // staging: 512 threads, 1 chunk K + 1 chunk V each; row r0, source chunk ch0,
  // stored at chunk ch0^(r0&7) (both-sides swizzle, reg-staged)
  const int r0 = t >> 3, ch0 = t & 7;
  const int lw = r0 * 64 + ((ch0 ^ (r0 & 7)) * 8);
  const unsigned short* Kg = QKV + base + 1024 + h * 64 + (size_t)r0 * 3072 + ch0 * 8;
  const unsigned short* Vg = VT + ((size_t)bh * 64 + r0) * 2048 + ch0 * 8;

  // swizzled frag-read offsets (16B chunks XOR q-row&7)
  const int kro0 = (g ^ cks) * 8, kro1 = ((4 + g) ^ cks) * 8;

  bf16x8 onef;
#pragma unroll
  for (int i = 0; i < 8; ++i) onef[i] = (__bf16)1.0f;

  const int qrow = q0b + w * 16 + c;
  const unsigned short* qp = QKV + base + (size_t)qrow * 3072 + h * 64 + g * 8;
  const bf16x8 qf0 = *(const bf16x8*)qp;
  const bf16x8 qf1 = *(const bf16x8*)(qp + 32);

  f32x4 o[4];
#pragma unroll
  for (int d = 0; d < 4; ++d) o[d] = (f32x4){0.f, 0.f, 0.f, 0.f};
  f32x4 ol = (f32x4){0.f, 0.f, 0.f, 0.f};
  float mrow = -1e30f;  // softmax state for q = qrow (scalar per lane)

  u16x8 kr, vr;
#define ATTN_LOAD(kt_)                                        \
  {                                                           \
    kr = *(const u16x8*)(Kg + (size_t)(kt_) * 64 * 3072);     \
    vr = *(const u16x8*)(Vg + (kt_) * 64);                    \
  }
#define ATTN_WRITE(buf)                                       \
  {                                                           \
    *(u16x8*)&Ks[buf][lw] = kr;                               \
    *(u16x8*)&Vs[buf][lw] = vr;                               \
  }

  ATTN_LOAD(0);
  ATTN_WRITE(0);
  if (nt > 1) ATTN_LOAD(1);
  __syncthreads();

  const int fsrc = g * 20;  // lane (c'=4g+r, g'=g) holds fac for q row 4g+r

  for (int j = 0; j < nt; ++j) {
    const int cur = j & 1;
    const int kbase = j * 64;
    const bool active = (kbase <= q0b + w * 16 + 15);  // wave-uniform

    if (active) {
      // S = K Q^T swapped: col=c=q, row=4g+r=key (exp2 domain)
      f32x4 s4[4];
      __builtin_amdgcn_s_setprio(1);
#pragma unroll
      for (int t16 = 0; t16 < 4; ++t16) {
        const int krow = (t16 * 16 + c) * 64;
        const bf16x8 kf0 = *(const bf16x8*)&Ks[cur][krow + kro0];
        const bf16x8 kf1 = *(const bf16x8*)&Ks[cur][krow + kro1];
        f32x4 a = (f32x4){0.f, 0.f, 0.f, 0.f};
        a = mfma16(kf0, qf0, a);
        a = mfma16(kf1, qf1, a);
        s4[t16] = a;
      }
      __builtin_amdgcn_s_setprio(0);
      if (kbase + 63 > qrow) {  // diagonal tile for this wave
#pragma unroll
        for (int t16 = 0; t16 < 4; ++t16)
#pragma unroll
          for (int r = 0; r < 4; ++r)
            if (kbase + t16 * 16 + 4 * g + r > qrow) s4[t16][r] = -1e30f;
      }
      // max over this tile's 64 keys for q=c: 16 in-reg + 2 shfl
      float mx = s4[0][0];
#pragma unroll
      for (int t16 = 0; t16 < 4; ++t16)
#pragma unroll
        for (int r = 0; r < 4; ++r) mx = fmaxf(mx, s4[t16][r]);
      mx = fmaxf(mx, __shfl_xor(mx, 16));
      mx = fmaxf(mx, __shfl_xor(mx, 32));
      const float mn = fmaxf(mrow, mx);
      const float fac = exp2f(mrow - mn);
      mrow = mn;
      // P = exp2(S - m), packed b64 writes (keys t16*16+4g..+3 contiguous)
#pragma unroll
      for (int t16 = 0; t16 < 4; ++t16) {
        bf16x4 pw;
#pragma unroll
        for (int r = 0; r < 4; ++r) pw[r] = (__bf16)exp2f(s4[t16][r] - mrow);
        *(bf16x4*)&Ps[w][c * 64 + (((2 * t16 + (g >> 1)) ^ cks) * 8) + (g & 1) * 4] = pw;
      }
      // redistribute fac to o-row layout (q = 4g+r)
      float fo[4];
#pragma unroll
      for (int r = 0; r < 4; ++r) fo[r] = __shfl(fac, fsrc + r);
#pragma unroll
      for (int d = 0; d < 4; ++d)
#pragma unroll
        for (int r = 0; r < 4; ++r) o[d][r] *= fo[r];
#pragma unroll
      for (int r = 0; r < 4; ++r) ol[r] *= fo[r];
      // O += P V ; l += P @ ones
      __builtin_amdgcn_s_setprio(1);
#pragma unroll
      for (int ks = 0; ks < 2; ++ks) {
        const int po = ((ks * 4 + g) ^ cks) * 8;
        const bf16x8 pf = *(const bf16x8*)&Ps[w][c * 64 + po];
#pragma unroll
        for (int d = 0; d < 4; ++d) {
          const bf16x8 vf = *(const bf16x8*)&Vs[cur][(d * 16 + c) * 64 + po];
          o[d] = mfma16(pf, vf, o[d]);
        }
        ol = mfma16(pf, onef, ol);
      }
      __builtin_amdgcn_s_setprio(0);
    }

    if (j + 1 < nt) {
      __syncthreads();       // prev iter's reads of buf[cur^1] done everywhere
      ATTN_WRITE(cur ^ 1);   // tile j+1 (vmcnt wait lands here, ~1 iter after issue)
      if (j + 2 < nt) ATTN_LOAD(j + 2);
      __syncthreads();       // buf[cur^1] visible before iter j+1 reads it
    }
  }
#pragma unroll
  for (int d = 0; d < 4; ++d)
#pragma unroll
    for (int r = 0; r < 4; ++r) {
      const float v = o[d][r] / ol[r];
      ctx[(size_t)(b * 2048 + q0b + w * 16 + g * 4 + r) * 1024 + h * 64 + d * 16 + c] = f2bf(v);
    }
#undef ATTN_LOAD
#undef ATTN_WRITE
}

// ---------------- launch ----------------

extern "C" void kernel_launch(void* const* d_in, const int* in_sizes, int n_in,
                              void* d_out, int out_size, void* d_ws, size_t ws_size,
                              hipStream_t stream) {
  const float* hidden = (const float*)d_in[0];
  const float* ln1g = (const float*)d_in[1];
  const float* ln1b = (const float*)d_in[2];
  const float* ln2g = (const float*)d_in[3];
  const float* ln2b = (const float*)d_in[4];
  const float* qU = (const float*)d_in[5];
  const float* qV = (const float*)d_in[6];
  const float* qb = (const float*)d_in[7];
  const float* kU = (const float*)d_in[8];
  const float* kV = (const float*)d_in[9];
  const float* kb = (const float*)d_in[10];
  const float* vU = (const float*)d_in[11];
  const float* vV = (const float*)d_in[12];
  const float* vb = (const float*)d_in[13];
  const float* outU = (const float*)d_in[14];
  const float* outV = (const float*)d_in[15];
  const float* outb = (const float*)d_in[16];
  const float* fc1U = (const float*)d_in[17];
  const float* fc1V = (const float*)d_in[18];
  const float* fc1b = (const float*)d_in[19];
  const float* fc2U = (const float*)d_in[20];
  const float* fc2V = (const float*)d_in[21];
  const float* fc2b = (const float*)d_in[22];
  float* out = (float*)d_out;

  // workspace carve, lifetime-based aliasing
  char* p = (char*)d_ws;
  unsigned short* x1x2 = (unsigned short*)p; p += (size_t)4096 * 1024 * 2;   // x1 (LN1), later x2 (LN2)
  unsigned short* WqT_t1 = (unsigned short*)p; p += (size_t)3072 * 1024 * 2; // Wqkv^T, later t1
  float* bqkv = (float*)p; p += 3072 * 4;
  char* bigA = p; p += (size_t)4096 * 3072 * 2 + (size_t)4096 * 1024 * 2;    // QKV + ctx, later hmid
  unsigned short* QKV = (unsigned short*)bigA;
  unsigned short* ctxb = (unsigned short*)(bigA + (size_t)4096 * 3072 * 2);
  unsigned short* hmid = (unsigned short*)bigA;
  char* wo = p; p += (size_t)1024 * 768 * 2 * 2 + (size_t)1024 * 1024 * 2;   // outU,outV^T,Wout^T, later t2
  unsigned short* outUb = (unsigned short*)wo;
  unsigned short* outVT = (unsigned short*)(wo + (size_t)1024 * 768 * 2);
  unsigned short* WoutT = (unsigned short*)(wo + (size_t)1024 * 768 * 2 * 2);
  unsigned short* t2 = (unsigned short*)wo;
  float* hbuf = (float*)p; p += (size_t)4096 * 1024 * 4;                     // h (fp32 residual); VT aliases pre-attn
  unsigned short* VT = (unsigned short*)hbuf;                                // [32][64][2048] bf16 = 8MB
  unsigned short* fc1UT = (unsigned short*)p; p += (size_t)512 * 1024 * 2;
  unsigned short* fc1VT = (unsigned short*)p; p += (size_t)4096 * 512 * 2;
  unsigned short* fc2UT = (unsigned short*)p; p += (size_t)512 * 4096 * 2;
  unsigned short* fc2VT = (unsigned short*)p; p += (size_t)1024 * 512 * 2;

  const dim3 b256(256);
  const dim3 tb(32, 8);

  // weight prep
  concat_bias_k<<<12, b256, 0, stream>>>(qb, kb, vb, bqkv);
  wqkv_pre_k<<<dim3(16, 48), b256, 0, stream>>>(qU, qV, kU, kV, vU, vV, WqT_t1);
  tcvt_k<<<dim3(32, 24), tb, 0, stream>>>(outV, outVT, 768, 1024);
  cvt_k<<<768, b256, 0, stream>>>(outU, outUb, 1024 * 768);
  tcvt_k<<<dim3(16, 32), tb, 0, stream>>>(fc1U, fc1UT, 1024, 512);
  tcvt_k<<<dim3(128, 16), tb, 0, stream>>>(fc1V, fc1VT, 512, 4096);
  tcvt_k<<<dim3(16, 128), tb, 0, stream>>>(fc2U, fc2UT, 4096, 512);
  tcvt_k<<<dim3(32, 16), tb, 0, stream>>>(fc2V, fc2VT, 512, 1024);

  // attention path
  ln_k<<<4096, b256, 0, stream>>>(hidden, ln1g, ln1b, x1x2);
  gemm_k<128, 128, 1, 1><<<dim3(24, 32), b256, 0, stream>>>(x1x2, WqT_t1, bqkv, nullptr, QKV, 4096, 3072, 1024);
  vtr_k<<<dim3(64, 2, 32), tb, 0, stream>>>(QKV, VT);
  gemm_k<128, 128, 0, 1><<<dim3(8, 8), b256, 0, stream>>>(outVT, outUb, nullptr, nullptr, WoutT, 1024, 1024, 768);
  attn_k<<<dim3(16, 32), dim3(512), 0, stream>>>(QKV, VT, ctxb);
  gemm_k<64, 128, 3, 0><<<dim3(8, 64), b256, 0, stream>>>(ctxb, WoutT, outb, hidden, hbuf, 4096, 1024, 1024);

  // MLP path
  ln_k<<<4096, b256, 0, stream>>>(hbuf, ln2g, ln2b, x1x2);
  gemm_k<64, 64, 0, 1><<<dim3(8, 64), b256, 0, stream>>>(x1x2, fc1UT, nullptr, nullptr, WqT_t1, 4096, 512, 1024);
  gemm_k<128, 128, 2, 1><<<dim3(32, 32), b256, 0, stream>>>(WqT_t1, fc1VT, fc1b, nullptr, hmid, 4096, 4096, 512);
  gemm_k<64, 64, 0, 1><<<dim3(8, 64), b256, 0, stream>>>(hmid, fc2UT, nullptr, nullptr, t2, 4096, 512, 4096);
  gemm_k<64, 128, 3, 0><<<dim3(8, 64), b256, 0, stream>>>(t2, fc2VT, fc2b, hbuf, out, 4096, 1024, 512);
}

// Round 10
// 258.791 us; speedup vs baseline: 1.8852x; 1.1260x over previous
//
#include <hip/hip_runtime.h>
#include <hip/hip_bf16.h>

typedef float f32x4 __attribute__((ext_vector_type(4)));
typedef __bf16 bf16x8 __attribute__((ext_vector_type(8)));
typedef __bf16 bf16x4 __attribute__((ext_vector_type(4)));
typedef unsigned short u16x8 __attribute__((ext_vector_type(8)));
typedef unsigned short u16x4 __attribute__((ext_vector_type(4)));

#define QSCALE 0.180336881f  /* 0.125 * log2(e): folds attn scale + exp2 domain into Q */

__device__ __forceinline__ unsigned short f2bf(float f) {
  union { float f; unsigned int u; } v; v.f = f;
  return (unsigned short)((v.u + 0x7FFFu + ((v.u >> 16) & 1u)) >> 16);
}

__device__ __forceinline__ f32x4 mfma16(bf16x8 a, bf16x8 b, f32x4 c) {
  return __builtin_amdgcn_mfma_f32_16x16x32_bf16(a, b, c, 0, 0, 0);
}

__device__ __forceinline__ void gload16(const unsigned short* g, unsigned short* l) {
  __builtin_amdgcn_global_load_lds(
      (const __attribute__((address_space(1))) void*)g,
      (__attribute__((address_space(3))) void*)l, 16, 0, 0);
}

// ---------------- small utility kernels ----------------

__global__ void concat_bias_k(const float* __restrict__ qb, const float* __restrict__ kb,
                              const float* __restrict__ vb, float* __restrict__ out) {
  const int i = blockIdx.x * 256 + threadIdx.x;
  if (i >= 3072) return;
  const float* s = (i < 1024) ? qb : (i < 2048 ? kb : vb);
  out[i] = s[i & 1023] * (i < 1024 ? QSCALE : 1.0f);
}

// fp32 [R,C] -> bf16 [C,R]
__global__ void tcvt_k(const float* __restrict__ in, unsigned short* __restrict__ out,
                       int R, int C) {
  __shared__ float tile[32][33];
  const int x = blockIdx.x * 32 + threadIdx.x;
  const int y0 = blockIdx.y * 32;
#pragma unroll
  for (int i = 0; i < 32; i += 8)
    tile[threadIdx.y + i][threadIdx.x] = in[(size_t)(y0 + threadIdx.y + i) * C + x];
  __syncthreads();
  const int ox = y0 + threadIdx.x;
  const int oy0 = blockIdx.x * 32;
#pragma unroll
  for (int i = 0; i < 32; i += 8)
    out[(size_t)(oy0 + threadIdx.y + i) * R + ox] = f2bf(tile[threadIdx.x][threadIdx.y + i]);
}

__global__ void cvt_k(const float* __restrict__ in, unsigned short* __restrict__ out, int n) {
  const int i = (blockIdx.x * 256 + threadIdx.x) * 4;
  if (i >= n) return;
  const f32x4 v = *(const f32x4*)(in + i);
  u16x4 o;
#pragma unroll
  for (int k = 0; k < 4; ++k) o[k] = f2bf(v[k]);
  *(u16x4*)(out + i) = o;
}

// V-transpose: QKV[b][s][2048 + h*64 + d] -> VT[(b*16+h)][d][s]  (bf16)
__global__ void vtr_k(const unsigned short* __restrict__ QKV, unsigned short* __restrict__ VT) {
  __shared__ unsigned short tile[32][33];
  const int bh = blockIdx.z, b = bh >> 4, h = bh & 15;
  const int s0 = blockIdx.x * 32, d0 = blockIdx.y * 32;
  const unsigned short* src = QKV + (size_t)b * 2048 * 3072 + 2048 + h * 64;
#pragma unroll
  for (int i = 0; i < 32; i += 8)
    tile[threadIdx.y + i][threadIdx.x] = src[(size_t)(s0 + threadIdx.y + i) * 3072 + d0 + threadIdx.x];
  __syncthreads();
  unsigned short* dst = VT + (size_t)bh * 64 * 2048;
#pragma unroll
  for (int i = 0; i < 32; i += 8)
    dst[(size_t)(d0 + threadIdx.y + i) * 2048 + s0 + threadIdx.x] = tile[threadIdx.x][threadIdx.y + i];
}

// Wqkv^T[(m*1024 + h*64 + e)*1024 + d] = sum_r U_m[d,h,r] * V_m[h,r,e]  (Q part scaled)
__global__ __launch_bounds__(256) void wqkv_pre_k(
    const float* __restrict__ qU, const float* __restrict__ qV,
    const float* __restrict__ kU, const float* __restrict__ kV,
    const float* __restrict__ vU, const float* __restrict__ vV,
    unsigned short* __restrict__ WT) {
  __shared__ float Us[64][48];
  __shared__ float Vs[48][64];
  const int m = blockIdx.y >> 4, h = blockIdx.y & 15;
  const int d0 = blockIdx.x * 64;
  const float* U = (m == 0) ? qU : (m == 1 ? kU : vU);
  const float* V = (m == 0) ? qV : (m == 1 ? kV : vV);
  const float qs = (m == 0) ? QSCALE : 1.0f;
  const int t = threadIdx.x;
  for (int idx = t; idx < 64 * 48; idx += 256) {
    const int d = idx / 48, r = idx - d * 48;
    Us[d][r] = U[(size_t)(d0 + d) * 768 + h * 48 + r];
  }
  for (int idx = t; idx < 48 * 64; idx += 256) {
    const int r = idx >> 6, e = idx & 63;
    Vs[r][e] = V[(h * 48 + r) * 64 + e];
  }
  __syncthreads();
  const int e = t & 63, dg = t >> 6;
  for (int j = 0; j < 16; ++j) {
    const int d = dg * 16 + j;
    float s = 0.f;
#pragma unroll
    for (int r = 0; r < 48; ++r) s = fmaf(Us[d][r], Vs[r][e], s);
    WT[(size_t)(m * 1024 + h * 64 + e) * 1024 + d0 + d] = f2bf(s * qs);
  }
}

// LayerNorm over D=1024, fp32 in, bf16 out. One block per row.
__global__ __launch_bounds__(256) void ln_k(
    const float* __restrict__ in, const float* __restrict__ gw,
    const float* __restrict__ bw, unsigned short* __restrict__ out) {
  const int row = blockIdx.x, t = threadIdx.x;
  const f32x4 v = *(const f32x4*)(in + (size_t)row * 1024 + t * 4);
  float s = v[0] + v[1] + v[2] + v[3];
  float ss = v[0] * v[0] + v[1] * v[1] + v[2] * v[2] + v[3] * v[3];
#pragma unroll
  for (int off = 1; off < 64; off <<= 1) {
    s += __shfl_xor(s, off);
    ss += __shfl_xor(ss, off);
  }
  __shared__ float red[8];
  if ((t & 63) == 0) { red[(t >> 6) * 2] = s; red[(t >> 6) * 2 + 1] = ss; }
  __syncthreads();
  s = red[0] + red[2] + red[4] + red[6];
  ss = red[1] + red[3] + red[5] + red[7];
  const float mean = s * (1.0f / 1024.0f);
  const float rstd = rsqrtf(ss * (1.0f / 1024.0f) - mean * mean + 1e-5f);
  const f32x4 g4 = *(const f32x4*)(gw + t * 4);
  const f32x4 b4 = *(const f32x4*)(bw + t * 4);
  u16x4 o;
#pragma unroll
  for (int i = 0; i < 4; ++i) o[i] = f2bf((v[i] - mean) * rstd * g4[i] + b4[i]);
  *(u16x4*)(out + (size_t)row * 1024 + t * 4) = o;
}

// bijective XCD chunking (m157/m204): XCD c gets a contiguous chunk of the
// bx-fastest block order -> same-A-panel (or same-head) blocks share one L2.
__device__ __forceinline__ void xcd_swz(int& bx, int& by, int nx, int ny) {
  const int nwg = nx * ny;
  if ((nwg & 7) == 0) {
    const int d = by * nx + bx;
    const int k = (d & 7) * (nwg >> 3) + (d >> 3);
    bx = k % nx;
    by = k / nx;
  }
}

// ---------------- generic bf16 MFMA GEMM ----------------
// C[M,N] = A[M,K] @ Bt[N,K]^T. 3-buffer global_load_lds pipeline, 2 tiles of
// prefetch in flight, counted s_waitcnt vmcnt(NL) + raw s_barrier per K-step
// (T3/T4: never drain vmcnt to 0 in steady state). Wait-BEFORE-barrier gives
// collective tile readiness. bf16 output bounces through per-wave LDS for
// coalesced b128 stores. Epilogue buffer is WAVE-LOCAL: columns indexed
// 0..BN/2-1 (fixed R9 bug: writing global col wn+.. overran the 72-stride).
template <int BM, int BN, int EPI, int OUTBF>
__global__ __launch_bounds__(256) void gemm_k(
    const unsigned short* __restrict__ A, const unsigned short* __restrict__ Bt,
    const float* __restrict__ bias, const float* __restrict__ resid,
    void* __restrict__ Cout, int M, int N, int K) {
  constexpr int MI = BM / 32;
  constexpr int FN = BN / 32;
  constexpr int NL = (BM == 128 ? 2 : 1) + (BN == 128 ? 2 : 1);  // gloads/thread/stage
  constexpr int SM_KLOOP = 3 * (BM + BN) * 32;
  constexpr int SM_EPI = OUTBF ? 4 * (BM / 2) * 72 : 0;
  constexpr int SME = SM_KLOOP > SM_EPI ? SM_KLOOP : SM_EPI;
  __shared__ unsigned short smem[SME];
  unsigned short* As = smem;                  // [3][BM*32]
  unsigned short* Bs = smem + 3 * BM * 32;    // [3][BN*32]
  int bxi = blockIdx.x, byi = blockIdx.y;
  xcd_swz(bxi, byi, gridDim.x, gridDim.y);
  const int t = threadIdx.x;
  const int lane = t & 63, wid = t >> 6;
  const int m0 = byi * BM, n0 = bxi * BN;
  const int wm = (wid >> 1) * (BM / 2), wn = (wid & 1) * (BN / 2);
  const int fr = lane & 15, fg = (lane >> 4) * 8;

  f32x4 acc[MI][FN];
#pragma unroll
  for (int i = 0; i < MI; ++i)
#pragma unroll
    for (int j = 0; j < FN; ++j) acc[i][j] = (f32x4){0.f, 0.f, 0.f, 0.f};

  const unsigned short* Ag0 = A + (size_t)(m0 + (t >> 2)) * K + (t & 3) * 8;
  const unsigned short* Ag1 = A + (size_t)(m0 + 64 + (t >> 2)) * K + (t & 3) * 8;
  const unsigned short* Bg0 = Bt + (size_t)(n0 + (t >> 2)) * K + (t & 3) * 8;
  const unsigned short* Bg1 = Bt + (size_t)(n0 + 64 + (t >> 2)) * K + (t & 3) * 8;
  const int l0 = t * 8;

#define GEMM_STAGE(buf, ke)                                             \
  {                                                                     \
    gload16(Ag0 + (ke), &As[(buf) * BM * 32 + l0]);                     \
    if (BM == 128) gload16(Ag1 + (ke), &As[(buf) * BM * 32 + l0 + 2048]); \
    gload16(Bg0 + (ke), &Bs[(buf) * BN * 32 + l0]);                     \
    if (BN == 128) gload16(Bg1 + (ke), &Bs[(buf) * BN * 32 + l0 + 2048]); \
  }

  const int nk = K >> 5;
  GEMM_STAGE(0, 0);
  if (nk > 1) GEMM_STAGE(1, 32);

  int cur = 0, sb = 2;
  for (int kt = 0; kt < nk; ++kt) {
    // collective readiness of tile kt: each wave waits its own count, THEN barrier.
    if (kt + 1 < nk)
      asm volatile("s_waitcnt vmcnt(%0)" ::"n"(NL) : "memory");
    else
      asm volatile("s_waitcnt vmcnt(0)" ::: "memory");
    __builtin_amdgcn_s_barrier();
    __builtin_amdgcn_sched_barrier(0);
    if (kt + 2 < nk) GEMM_STAGE(sb, (kt + 2) * 32);  // buf read at iter kt-1; safe after barrier
    bf16x8 af[MI], bfr[FN];
#pragma unroll
    for (int i = 0; i < MI; ++i)
      af[i] = *(const bf16x8*)&As[cur * BM * 32 + (wm + i * 16 + fr) * 32 + fg];
#pragma unroll
    for (int j = 0; j < FN; ++j)
      bfr[j] = *(const bf16x8*)&Bs[cur * BN * 32 + (wn + j * 16 + fr) * 32 + fg];
#pragma unroll
    for (int i = 0; i < MI; ++i)
#pragma unroll
      for (int j = 0; j < FN; ++j) acc[i][j] = mfma16(af[i], bfr[j], acc[i][j]);
    cur = (cur == 2) ? 0 : cur + 1;
    sb = (sb == 2) ? 0 : sb + 1;
  }
#undef GEMM_STAGE

  if (OUTBF) {
    __syncthreads();  // all waves out of the K-loop before smem reuse
    unsigned short* eb = smem + wid * ((BM / 2) * 72);  // per-wave [BM/2][72] bf16
#pragma unroll
    for (int j = 0; j < FN; ++j) {
      const int colL = j * 16 + fr;                     // wave-local column
      const float bval = (EPI >= 1) ? bias[n0 + wn + colL] : 0.0f;
#pragma unroll
      for (int i = 0; i < MI; ++i) {
#pragma unroll
        for (int r = 0; r < 4; ++r) {
          const int rl = i * 16 + ((lane >> 4) << 2) + r;
          float v = acc[i][j][r] + bval;
          if (EPI == 2) {  // gelu tanh-approx: v * sigmoid(2z)
            const float z = 0.7978845608028654f * (v + 0.044715f * v * v * v);
            v = v - v / (__expf(2.0f * z) + 1.0f);
          }
          eb[rl * 72 + colL] = f2bf(v);
        }
      }
    }
    __builtin_amdgcn_s_barrier();  // wave-local buffer, but keep stores after writes scheduling-wise
    // coalesced b128 stores: CH 16B-chunks per row
    constexpr int CH = (BN / 2) / 8;
    constexpr int RPI = 64 / CH;             // rows per pass
    const int c2 = lane % CH, r2b = lane / CH;
    unsigned short* Cg = (unsigned short*)Cout;
#pragma unroll
    for (int it = 0; it < (BM / 2) / RPI; ++it) {
      const int r2 = r2b + it * RPI;
      const u16x8 vv = *(const u16x8*)&eb[r2 * 72 + c2 * 8];
      *(u16x8*)&Cg[(size_t)(m0 + wm + r2) * N + n0 + wn + c2 * 8] = vv;
    }
  } else {
#pragma unroll
    for (int j = 0; j < FN; ++j) {
      const int col = n0 + wn + j * 16 + fr;
      const float bval = (EPI >= 1) ? bias[col] : 0.0f;
#pragma unroll
      for (int i = 0; i < MI; ++i) {
#pragma unroll
        for (int r = 0; r < 4; ++r) {
          const int row = m0 + wm + i * 16 + ((lane >> 4) << 2) + r;
          float v = acc[i][j][r] + bval;
          if (EPI == 3) v += resid[(size_t)row * N + col];
          ((float*)Cout)[(size_t)row * N + col] = v;
        }
      }
    }
  }
}

// ---------------- causal flash attention (unchanged from R8) ----------------
__global__ __launch_bounds__(512) void attn_k(
    const unsigned short* __restrict__ QKV, const unsigned short* __restrict__ VT,
    unsigned short* __restrict__ ctx) {
  __shared__ unsigned short Ks[2][64 * 64];
  __shared__ unsigned short Vs[2][64 * 64];
  __shared__ unsigned short Ps[8][16 * 64];  // per-wave P, 16B-chunk swizzled by q&7
  int bxi = blockIdx.x, byi = blockIdx.y;
  xcd_swz(bxi, byi, 16, 32);
  const int qi = ((byi >> 1) & 1) ? (15 - bxi) : bxi;
  const int bh = byi, b = bh >> 4, h = bh & 15;
  const int nt = 2 * qi + 2;
  const int q0b = qi * 128;
  const int t = threadIdx.x, lane = t & 63, w = t >> 6;
  const int g = lane >> 4, c = lane & 15;
  const int cks = c & 7;
  const size_t base = (size_t)b * 2048 * 3072;

  const int r0 = t >> 3, ch0 = t & 7;
  const int lw = r0 * 64 + ((ch0 ^ (r0 & 7)) * 8);
  const unsigned short* Kg = QKV + base + 1024 + h * 64 + (size_t)r0 * 3072 + ch0 * 8;
  const unsigned short* Vg = VT + ((size_t)bh * 64 + r0) * 2048 + ch0 * 8;

  const int kro0 = (g ^ cks) * 8, kro1 = ((4 + g) ^ cks) * 8;

  bf16x8 onef;
#pragma unroll
  for (int i = 0; i < 8; ++i) onef[i] = (__bf16)1.0f;

  const int qrow = q0b + w * 16 + c;
  const unsigned short* qp = QKV + base + (size_t)qrow * 3072 + h * 64 + g * 8;
  const bf16x8 qf0 = *(const bf16x8*)qp;
  const bf16x8 qf1 = *(const bf16x8*)(qp + 32);

  f32x4 o[4];
#pragma unroll
  for (int d = 0; d < 4; ++d) o[d] = (f32x4){0.f, 0.f, 0.f, 0.f};
  f32x4 ol = (f32x4){0.f, 0.f, 0.f, 0.f};
  float mrow = -1e30f;

  u16x8 kr, vr;
#define ATTN_LOAD(kt_)                                        \
  {                                                           \
    kr = *(const u16x8*)(Kg + (size_t)(kt_) * 64 * 3072);     \
    vr = *(const u16x8*)(Vg + (kt_) * 64);                    \
  }
#define ATTN_WRITE(buf)                                       \
  {                                                           \
    *(u16x8*)&Ks[buf][lw] = kr;                               \
    *(u16x8*)&Vs[buf][lw] = vr;                               \
  }

  ATTN_LOAD(0);
  ATTN_WRITE(0);
  if (nt > 1) ATTN_LOAD(1);
  __syncthreads();

  const int fsrc = g * 20;

  for (int j = 0; j < nt; ++j) {
    const int cur = j & 1;
    const int kbase = j * 64;
    const bool active = (kbase <= q0b + w * 16 + 15);

    if (active) {
      f32x4 s4[4];
      __builtin_amdgcn_s_setprio(1);
#pragma unroll
      for (int t16 = 0; t16 < 4; ++t16) {
        const int krow = (t16 * 16 + c) * 64;
        const bf16x8 kf0 = *(const bf16x8*)&Ks[cur][krow + kro0];
        const bf16x8 kf1 = *(const bf16x8*)&Ks[cur][krow + kro1];
        f32x4 a = (f32x4){0.f, 0.f, 0.f, 0.f};
        a = mfma16(kf0, qf0, a);
        a = mfma16(kf1, qf1, a);
        s4[t16] = a;
      }
      __builtin_amdgcn_s_setprio(0);
      if (kbase + 63 > qrow) {
#pragma unroll
        for (int t16 = 0; t16 < 4; ++t16)
#pragma unroll
          for (int r = 0; r < 4; ++r)
            if (kbase + t16 * 16 + 4 * g + r > qrow) s4[t16][r] = -1e30f;
      }
      float mx = s4[0][0];
#pragma unroll
      for (int t16 = 0; t16 < 4; ++t16)
#pragma unroll
        for (int r = 0; r < 4; ++r) mx = fmaxf(mx, s4[t16][r]);
      mx = fmaxf(mx, __shfl_xor(mx, 16));
      mx = fmaxf(mx, __shfl_xor(mx, 32));
      const float mn = fmaxf(mrow, mx);
      const float fac = exp2f(mrow - mn);
      mrow = mn;
#pragma unroll
      for (int t16 = 0; t16 < 4; ++t16) {
        bf16x4 pw;
#pragma unroll
        for (int r = 0; r < 4; ++r) pw[r] = (__bf16)exp2f(s4[t16][r] - mrow);
        *(bf16x4*)&Ps[w][c * 64 + (((2 * t16 + (g >> 1)) ^ cks) * 8) + (g & 1) * 4] = pw;
      }
      float fo[4];
#pragma unroll
      for (int r = 0; r < 4; ++r) fo[r] = __shfl(fac, fsrc + r);
#pragma unroll
      for (int d = 0; d < 4; ++d)
#pragma unroll
        for (int r = 0; r < 4; ++r) o[d][r] *= fo[r];
#pragma unroll
      for (int r = 0; r < 4; ++r) ol[r] *= fo[r];
      __builtin_amdgcn_s_setprio(1);
#pragma unroll
      for (int ks = 0; ks < 2; ++ks) {
        const int po = ((ks * 4 + g) ^ cks) * 8;
        const bf16x8 pf = *(const bf16x8*)&Ps[w][c * 64 + po];
#pragma unroll
        for (int d = 0; d < 4; ++d) {
          const bf16x8 vf = *(const bf16x8*)&Vs[cur][(d * 16 + c) * 64 + po];
          o[d] = mfma16(pf, vf, o[d]);
        }
        ol = mfma16(pf, onef, ol);
      }
      __builtin_amdgcn_s_setprio(0);
    }

    if (j + 1 < nt) {
      __syncthreads();
      ATTN_WRITE(cur ^ 1);
      if (j + 2 < nt) ATTN_LOAD(j + 2);
      __syncthreads();
    }
  }
#pragma unroll
  for (int d = 0; d < 4; ++d)
#pragma unroll
    for (int r = 0; r < 4; ++r) {
      const float v = o[d][r] / ol[r];
      ctx[(size_t)(b * 2048 + q0b + w * 16 + g * 4 + r) * 1024 + h * 64 + d * 16 + c] = f2bf(v);
    }
#undef ATTN_LOAD
#undef ATTN_WRITE
}

// ---------------- launch ----------------

extern "C" void kernel_launch(void* const* d_in, const int* in_sizes, int n_in,
                              void* d_out, int out_size, void* d_ws, size_t ws_size,
                              hipStream_t stream) {
  const float* hidden = (const float*)d_in[0];
  const float* ln1g = (const float*)d_in[1];
  const float* ln1b = (const float*)d_in[2];
  const float* ln2g = (const float*)d_in[3];
  const float* ln2b = (const float*)d_in[4];
  const float* qU = (const float*)d_in[5];
  const float* qV = (const float*)d_in[6];
  const float* qb = (const float*)d_in[7];
  const float* kU = (const float*)d_in[8];
  const float* kV = (const float*)d_in[9];
  const float* kb = (const float*)d_in[10];
  const float* vU = (const float*)d_in[11];
  const float* vV = (const float*)d_in[12];
  const float* vb = (const float*)d_in[13];
  const float* outU = (const float*)d_in[14];
  const float* outV = (const float*)d_in[15];
  const float* outb = (const float*)d_in[16];
  const float* fc1U = (const float*)d_in[17];
  const float* fc1V = (const float*)d_in[18];
  const float* fc1b = (const float*)d_in[19];
  const float* fc2U = (const float*)d_in[20];
  const float* fc2V = (const float*)d_in[21];
  const float* fc2b = (const float*)d_in[22];
  float* out = (float*)d_out;

  // workspace carve, lifetime-based aliasing
  char* p = (char*)d_ws;
  unsigned short* x1x2 = (unsigned short*)p; p += (size_t)4096 * 1024 * 2;   // x1 (LN1), later x2 (LN2)
  unsigned short* WqT_t1 = (unsigned short*)p; p += (size_t)3072 * 1024 * 2; // Wqkv^T, later t1
  float* bqkv = (float*)p; p += 3072 * 4;
  char* bigA = p; p += (size_t)4096 * 3072 * 2 + (size_t)4096 * 1024 * 2;    // QKV + ctx, later hmid
  unsigned short* QKV = (unsigned short*)bigA;
  unsigned short* ctxb = (unsigned short*)(bigA + (size_t)4096 * 3072 * 2);
  unsigned short* hmid = (unsigned short*)bigA;
  char* wo = p; p += (size_t)1024 * 768 * 2 * 2 + (size_t)1024 * 1024 * 2;   // outU,outV^T,Wout^T, later t2
  unsigned short* outUb = (unsigned short*)wo;
  unsigned short* outVT = (unsigned short*)(wo + (size_t)1024 * 768 * 2);
  unsigned short* WoutT = (unsigned short*)(wo + (size_t)1024 * 768 * 2 * 2);
  unsigned short* t2 = (unsigned short*)wo;
  float* hbuf = (float*)p; p += (size_t)4096 * 1024 * 4;                     // h (fp32 residual); VT aliases pre-attn
  unsigned short* VT = (unsigned short*)hbuf;                                // [32][64][2048] bf16 = 8MB
  unsigned short* fc1UT = (unsigned short*)p; p += (size_t)512 * 1024 * 2;
  unsigned short* fc1VT = (unsigned short*)p; p += (size_t)4096 * 512 * 2;
  unsigned short* fc2UT = (unsigned short*)p; p += (size_t)512 * 4096 * 2;
  unsigned short* fc2VT = (unsigned short*)p; p += (size_t)1024 * 512 * 2;

  const dim3 b256(256);
  const dim3 tb(32, 8);

  // weight prep
  concat_bias_k<<<12, b256, 0, stream>>>(qb, kb, vb, bqkv);
  wqkv_pre_k<<<dim3(16, 48), b256, 0, stream>>>(qU, qV, kU, kV, vU, vV, WqT_t1);
  tcvt_k<<<dim3(32, 24), tb, 0, stream>>>(outV, outVT, 768, 1024);
  cvt_k<<<768, b256, 0, stream>>>(outU, outUb, 1024 * 768);
  tcvt_k<<<dim3(16, 32), tb, 0, stream>>>(fc1U, fc1UT, 1024, 512);
  tcvt_k<<<dim3(128, 16), tb, 0, stream>>>(fc1V, fc1VT, 512, 4096);
  tcvt_k<<<dim3(16, 128), tb, 0, stream>>>(fc2U, fc2UT, 4096, 512);
  tcvt_k<<<dim3(32, 16), tb, 0, stream>>>(fc2V, fc2VT, 512, 1024);

  // attention path
  ln_k<<<4096, b256, 0, stream>>>(hidden, ln1g, ln1b, x1x2);
  gemm_k<128, 128, 1, 1><<<dim3(24, 32), b256, 0, stream>>>(x1x2, WqT_t1, bqkv, nullptr, QKV, 4096, 3072, 1024);
  vtr_k<<<dim3(64, 2, 32), tb, 0, stream>>>(QKV, VT);
  gemm_k<128, 128, 0, 1><<<dim3(8, 8), b256, 0, stream>>>(outVT, outUb, nullptr, nullptr, WoutT, 1024, 1024, 768);
  attn_k<<<dim3(16, 32), dim3(512), 0, stream>>>(QKV, VT, ctxb);
  gemm_k<64, 128, 3, 0><<<dim3(8, 64), b256, 0, stream>>>(ctxb, WoutT, outb, hidden, hbuf, 4096, 1024, 1024);

  // MLP path
  ln_k<<<4096, b256, 0, stream>>>(hbuf, ln2g, ln2b, x1x2);
  gemm_k<64, 64, 0, 1><<<dim3(8, 64), b256, 0, stream>>>(x1x2, fc1UT, nullptr, nullptr, WqT_t1, 4096, 512, 1024);
  gemm_k<128, 128, 2, 1><<<dim3(32, 32), b256, 0, stream>>>(WqT_t1, fc1VT, fc1b, nullptr, hmid, 4096, 4096, 512);
  gemm_k<64, 64, 0, 1><<<dim3(8, 64), b256, 0, stream>>>(hmid, fc2UT, nullptr, nullptr, t2, 4096, 512, 4096);
  gemm_k<64, 128, 3, 0><<<dim3(8, 64), b256, 0, stream>>>(t2, fc2VT, fc2b, hbuf, out, 4096, 1024, 512);
}